// Round 1
// baseline (673.922 us; speedup 1.0000x reference)
//
#include <hip/hip_runtime.h>
#include <hip/hip_fp16.h>

#define NBLK 1024        // blocks for edge-streaming passes
#define BTHREADS 256
#define BB 9             // bucket bits: 512 nodes per bucket (grid = N/512 blocks)
#define BSZ (1 << BB)
#define BMASK (BSZ - 1)
#define MAXNB 2048       // max buckets supported (N <= 1,048,576)
#define GTHREADS 512     // gather/accumulate kernels

// ---------------- helpers ----------------
__device__ __forceinline__ int detect64(const int* __restrict__ ei) {
    return (ei[1] | ei[3] | ei[5] | ei[7] | ei[9] | ei[11] | ei[13] | ei[15]) == 0;
}
__device__ __forceinline__ int load_src(const int* __restrict__ ei, int e, int is64) {
    return is64 ? ei[2 * (size_t)e] : ei[(size_t)e];
}
__device__ __forceinline__ int load_dst(const int* __restrict__ ei, int E, int e, int is64) {
    return is64 ? ei[2 * ((size_t)E + e)] : ei[(size_t)E + e];
}
__device__ __forceinline__ unsigned int h2u(__half2 h) {
    union { __half2 h; unsigned int u; } c; c.h = h; return c.u;
}
__device__ __forceinline__ __half2 u2h(unsigned int u) {
    union { __half2 h; unsigned int u; } c; c.u = u; return c.h;
}

// Pass 1: per-block histogram of dst buckets. No global atomics.
__global__ __launch_bounds__(BTHREADS) void pass1_hist(
    const int* __restrict__ ei, int E, int NB, unsigned int* __restrict__ off) {
    __shared__ unsigned int hist[MAXNB];
    int t = threadIdx.x, blk = blockIdx.x;
    for (int u = t; u < MAXNB; u += BTHREADS) hist[u] = 0;
    __syncthreads();
    int is64 = detect64(ei);
    int chunk = (E + NBLK - 1) / NBLK;
    int lo = blk * chunk;
    int hi = lo + chunk; if (hi > E) hi = E;
    for (int e = lo + t; e < hi; e += BTHREADS) {
        int d = load_dst(ei, E, e, is64);
        atomicAdd(&hist[d >> BB], 1u);
    }
    __syncthreads();
    for (int u = t; u < NB; u += BTHREADS) off[(size_t)u * NBLK + blk] = hist[u];
}

// Scan A: per bucket, exclusive scan over the 1024 per-block counts.
__global__ __launch_bounds__(BTHREADS) void scan_blocks(
    unsigned int* __restrict__ off, unsigned int* __restrict__ btot) {
    __shared__ unsigned int s[BTHREADS];
    int b = blockIdx.x, t = threadIdx.x;
    unsigned int* row = off + (size_t)b * NBLK;
    unsigned int v0 = row[4 * t], v1 = row[4 * t + 1], v2 = row[4 * t + 2], v3 = row[4 * t + 3];
    unsigned int sum = v0 + v1 + v2 + v3;
    s[t] = sum;
    __syncthreads();
    for (int o = 1; o < BTHREADS; o <<= 1) {
        unsigned int x = (t >= o) ? s[t - o] : 0;
        __syncthreads();
        s[t] += x;
        __syncthreads();
    }
    unsigned int base = t ? s[t - 1] : 0;
    row[4 * t] = base;
    row[4 * t + 1] = base + v0;
    row[4 * t + 2] = base + v0 + v1;
    row[4 * t + 3] = base + v0 + v1 + v2;
    if (t == BTHREADS - 1) btot[b] = s[BTHREADS - 1];
}

// Scan B: exclusive scan over bucket totals (NB <= 2048, 8 per thread).
__global__ __launch_bounds__(BTHREADS) void scan_buckets(
    const unsigned int* __restrict__ btot, unsigned int* __restrict__ bbase, int NB) {
    __shared__ unsigned int s[BTHREADS];
    int t = threadIdx.x;
    unsigned int v[8];
    unsigned int sum = 0;
#pragma unroll
    for (int j = 0; j < 8; ++j) {
        int idx = 8 * t + j;
        v[j] = (idx < NB) ? btot[idx] : 0;
        sum += v[j];
    }
    s[t] = sum;
    __syncthreads();
    for (int o = 1; o < BTHREADS; o <<= 1) {
        unsigned int x = (t >= o) ? s[t - o] : 0;
        __syncthreads();
        s[t] += x;
        __syncthreads();
    }
    unsigned int base = t ? s[t - 1] : 0;
#pragma unroll
    for (int j = 0; j < 8; ++j) {
        int idx = 8 * t + j;
        if (idx < NB) bbase[idx] = base;
        base += v[j];
    }
}

// Pass 2: scatter packed records (src<<BB | dstlow) into bucket-contiguous ebin.
__global__ __launch_bounds__(BTHREADS) void pass2_scatter(
    const int* __restrict__ ei, int E, int NB,
    const unsigned int* __restrict__ off, const unsigned int* __restrict__ bbase,
    unsigned int* __restrict__ ebin) {
    __shared__ unsigned int cur[MAXNB];
    int t = threadIdx.x, blk = blockIdx.x;
    for (int u = t; u < NB; u += BTHREADS)
        cur[u] = bbase[u] + off[(size_t)u * NBLK + blk];
    __syncthreads();
    int is64 = detect64(ei);
    int chunk = (E + NBLK - 1) / NBLK;
    int lo = blk * chunk;
    int hi = lo + chunk; if (hi > E) hi = E;
    for (int e = lo + t; e < hi; e += BTHREADS) {
        int s = load_src(ei, e, is64);
        int d = load_dst(ei, E, e, is64);
        unsigned int pos = atomicAdd(&cur[d >> BB], 1u);
        ebin[pos] = ((unsigned int)s << BB) | (unsigned int)(d & BMASK);
    }
}

// Per bucket: degree histogram in LDS -> dinv (f32), xs = half4(x * dinv) (uint2).
__global__ __launch_bounds__(GTHREADS) void deg_prep(
    const unsigned int* __restrict__ ebin, const unsigned int* __restrict__ bbase,
    const unsigned int* __restrict__ btot, const float4* __restrict__ x,
    float* __restrict__ dinv, uint2* __restrict__ xs, int N) {
    __shared__ unsigned int dcnt[BSZ];
    int b = blockIdx.x, t = threadIdx.x;
    for (int j = t; j < BSZ; j += GTHREADS) dcnt[j] = 0;
    __syncthreads();
    unsigned int base = bbase[b];
    int cnt = (int)btot[b];
    for (int i = t; i < cnt; i += GTHREADS)
        atomicAdd(&dcnt[ebin[base + i] & BMASK], 1u);
    __syncthreads();
    int g0 = b << BB;
    int nn = N - g0; if (nn > BSZ) nn = BSZ;
    for (int j = t; j < nn; j += GTHREADS) {
        int g = g0 + j;
        float di = rsqrtf((float)(dcnt[j] + 1u));
        dinv[g] = di;
        float4 v = x[g];
        uint2 p;
        p.x = h2u(__halves2half2(__float2half_rn(v.x * di), __float2half_rn(v.y * di)));
        p.y = h2u(__halves2half2(__float2half_rn(v.z * di), __float2half_rn(v.w * di)));
        xs[g] = p;
    }
}

// Layer 1 FUSED: gather/accumulate into LDS, then MLP epilogue in-block.
// (buckets are block-exclusive, so acc[] is complete at the barrier; the
//  64-wide MLP is free VALU work under the gather latency: VALUBusy was 1.6%)
__global__ __launch_bounds__(GTHREADS, 8) void l1_gather_mlp(
    const unsigned int* __restrict__ ebin, const unsigned int* __restrict__ bbase,
    const unsigned int* __restrict__ btot,
    const uint2* __restrict__ xs, const float* __restrict__ dinv,
    const float* __restrict__ W1, const float* __restrict__ b1,
    const float* __restrict__ W2, unsigned int* __restrict__ ps, int N) {
    __shared__ float acc[BSZ][4];   // 8 KB
    __shared__ float sW1[256];
    __shared__ float sb1[64];
    __shared__ float sW2[128];
    int b = blockIdx.x, t = threadIdx.x;
    if (t < 256) sW1[t] = W1[t];
    else if (t < 320) sb1[t - 256] = b1[t - 256];
    else if (t < 448) sW2[t - 320] = W2[t - 320];
    {
        float* p = &acc[0][0];
        for (int j = t; j < BSZ * 4; j += GTHREADS) p[j] = 0.0f;
    }
    __syncthreads();
    unsigned int base = bbase[b];
    int cnt = (int)btot[b];
    for (int i0 = 8 * t; i0 < cnt; i0 += 8 * GTHREADS) {
        int m = cnt - i0; if (m > 8) m = 8;
        unsigned int rec[8];
        uint2 raw[8];
#pragma unroll
        for (int j = 0; j < 8; ++j) if (j < m) rec[j] = ebin[base + i0 + j];
#pragma unroll
        for (int j = 0; j < 8; ++j) if (j < m) raw[j] = xs[rec[j] >> BB];
#pragma unroll
        for (int j = 0; j < 8; ++j) if (j < m) {
            int d = rec[j] & BMASK;
            __half2 h01 = u2h(raw[j].x), h23 = u2h(raw[j].y);
            atomicAdd(&acc[d][0], __half2float(__low2half(h01)));
            atomicAdd(&acc[d][1], __half2float(__high2half(h01)));
            atomicAdd(&acc[d][2], __half2float(__low2half(h23)));
            atomicAdd(&acc[d][3], __half2float(__high2half(h23)));
        }
    }
    __syncthreads();
    int g0 = b << BB;
    int nn = N - g0; if (nn > BSZ) nn = BSZ;
    if (t < nn) {
        int g = g0 + t;
        float di = dinv[g];
        uint2 raw = xs[g];  // self-loop (quantized, consistent)
        __half2 h01 = u2h(raw.x), h23 = u2h(raw.y);
        float ax = (acc[t][0] + __half2float(__low2half(h01))) * di;
        float ay = (acc[t][1] + __half2float(__high2half(h01))) * di;
        float az = (acc[t][2] + __half2float(__low2half(h23))) * di;
        float aw = (acc[t][3] + __half2float(__high2half(h23))) * di;
        float p0 = 0.0f, p1 = 0.0f;
#pragma unroll
        for (int k = 0; k < 64; ++k) {
            float h = fmaf(ax, sW1[k],
                      fmaf(ay, sW1[64 + k],
                      fmaf(az, sW1[128 + k],
                      fmaf(aw, sW1[192 + k], sb1[k]))));
            h = fmaxf(h, 0.0f);
            p0 = fmaf(h, sW2[2 * k + 0], p0);
            p1 = fmaf(h, sW2[2 * k + 1], p1);
        }
        ps[g] = h2u(__halves2half2(__float2half_rn(p0 * di), __float2half_rn(p1 * di)));
    }
}

// Layer 2: gather half2 ps[src] (4 MB table), LDS accumulate, epilogue. 8-deep ILP.
__global__ __launch_bounds__(GTHREADS, 8) void l2_agg(
    const unsigned int* __restrict__ ebin, const unsigned int* __restrict__ bbase,
    const unsigned int* __restrict__ btot,
    const unsigned int* __restrict__ ps, const float* __restrict__ dinv,
    const float* __restrict__ b2, float2* __restrict__ out, int N) {
    __shared__ float acc[BSZ][2];   // 4 KB
    int b = blockIdx.x, t = threadIdx.x;
    {
        float* p = &acc[0][0];
        for (int j = t; j < BSZ * 2; j += GTHREADS) p[j] = 0.0f;
    }
    __syncthreads();
    unsigned int base = bbase[b];
    int cnt = (int)btot[b];
    for (int i0 = 8 * t; i0 < cnt; i0 += 8 * GTHREADS) {
        int m = cnt - i0; if (m > 8) m = 8;
        unsigned int rec[8];
        unsigned int raw[8];
#pragma unroll
        for (int j = 0; j < 8; ++j) if (j < m) rec[j] = ebin[base + i0 + j];
#pragma unroll
        for (int j = 0; j < 8; ++j) if (j < m) raw[j] = ps[rec[j] >> BB];
#pragma unroll
        for (int j = 0; j < 8; ++j) if (j < m) {
            int d = rec[j] & BMASK;
            __half2 h = u2h(raw[j]);
            atomicAdd(&acc[d][0], __half2float(__low2half(h)));
            atomicAdd(&acc[d][1], __half2float(__high2half(h)));
        }
    }
    __syncthreads();
    int g0 = b << BB;
    int nn = N - g0; if (nn > BSZ) nn = BSZ;
    float c0 = b2[0], c1 = b2[1];
    for (int j = t; j < nn; j += GTHREADS) {
        int g = g0 + j;
        float di = dinv[g];
        __half2 h = u2h(ps[g]);  // self-loop
        float2 r;
        r.x = fmaf(acc[j][0] + __half2float(__low2half(h)), di, c0);
        r.y = fmaf(acc[j][1] + __half2float(__high2half(h)), di, c1);
        out[g] = r;
    }
}

static inline size_t align256(size_t v) { return (v + 255) & ~(size_t)255; }

extern "C" void kernel_launch(void* const* d_in, const int* in_sizes, int n_in,
                              void* d_out, int out_size, void* d_ws, size_t ws_size,
                              hipStream_t stream) {
    const float* x  = (const float*)d_in[0];
    const int*   ei = (const int*)d_in[1];
    const float* W1 = (const float*)d_in[2];
    const float* b1 = (const float*)d_in[3];
    const float* W2 = (const float*)d_in[4];
    const float* b2 = (const float*)d_in[5];

    const int N = in_sizes[0] / 4;
    const int E = in_sizes[1] / 2;
    const int NB = (N + BSZ - 1) >> BB;

    char* ws = (char*)d_ws;
    size_t o = 0;
    unsigned int* ebin  = (unsigned int*)(ws + o); o = align256(o + (size_t)E * 4);
    unsigned int* off   = (unsigned int*)(ws + o); o = align256(o + (size_t)MAXNB * NBLK * 4);
    unsigned int* btot  = (unsigned int*)(ws + o); o = align256(o + (size_t)MAXNB * 4);
    unsigned int* bbase = (unsigned int*)(ws + o); o = align256(o + (size_t)MAXNB * 4);
    float*        dinv  = (float*)(ws + o);        o = align256(o + (size_t)N * 4);
    uint2*        xs    = (uint2*)(ws + o);        o = align256(o + (size_t)N * 8);
    unsigned int* ps    = (unsigned int*)(ws + o); o = align256(o + (size_t)N * 4);

    pass1_hist<<<NBLK, BTHREADS, 0, stream>>>(ei, E, NB, off);
    scan_blocks<<<NB, BTHREADS, 0, stream>>>(off, btot);
    scan_buckets<<<1, BTHREADS, 0, stream>>>(btot, bbase, NB);
    pass2_scatter<<<NBLK, BTHREADS, 0, stream>>>(ei, E, NB, off, bbase, ebin);
    deg_prep<<<NB, GTHREADS, 0, stream>>>(ebin, bbase, btot, (const float4*)x, dinv, xs, N);
    l1_gather_mlp<<<NB, GTHREADS, 0, stream>>>(ebin, bbase, btot, xs, dinv, W1, b1, W2, ps, N);
    l2_agg<<<NB, GTHREADS, 0, stream>>>(ebin, bbase, btot, ps, dinv, b2, (float2*)d_out, N);
}

// Round 2
// 631.181 us; speedup vs baseline: 1.0677x; 1.0677x over previous
//
#include <hip/hip_runtime.h>
#include <hip/hip_fp16.h>

#define NBLK 1024        // blocks for edge-streaming passes
#define BTHREADS 256
#define BB 11            // bucket bits: 2048 nodes per bucket
#define BSZ (1 << BB)
#define BMASK (BSZ - 1)
#define MAXNB 2048       // max KEYS (= buckets * slices); N*S <= 2048*2048
#define GTHREADS 512     // gather/accumulate kernels

// ---------------- helpers ----------------
__device__ __forceinline__ int detect64(const int* __restrict__ ei) {
    return (ei[1] | ei[3] | ei[5] | ei[7] | ei[9] | ei[11] | ei[13] | ei[15]) == 0;
}
__device__ __forceinline__ int load_src(const int* __restrict__ ei, int e, int is64) {
    return is64 ? ei[2 * (size_t)e] : ei[(size_t)e];
}
__device__ __forceinline__ int load_dst(const int* __restrict__ ei, int E, int e, int is64) {
    return is64 ? ei[2 * ((size_t)E + e)] : ei[(size_t)E + e];
}
__device__ __forceinline__ unsigned int h2u(__half2 h) {
    union { __half2 h; unsigned int u; } c; c.h = h; return c.u;
}
__device__ __forceinline__ __half2 u2h(unsigned int u) {
    union { __half2 h; unsigned int u; } c; c.u = u; return c.h;
}

// Pass 1: per-block histogram of (dst-bucket, src-slice) keys. No global atomics.
__global__ __launch_bounds__(BTHREADS) void pass1_hist(
    const int* __restrict__ ei, int E, int NKEY, int S, int sshift,
    unsigned int* __restrict__ off) {
    __shared__ unsigned int hist[MAXNB];
    int t = threadIdx.x, blk = blockIdx.x;
    for (int u = t; u < MAXNB; u += BTHREADS) hist[u] = 0;
    __syncthreads();
    int is64 = detect64(ei);
    int chunk = (E + NBLK - 1) / NBLK;
    int lo = blk * chunk;
    int hi = lo + chunk; if (hi > E) hi = E;
    for (int e = lo + t; e < hi; e += BTHREADS) {
        int s = load_src(ei, e, is64);
        int d = load_dst(ei, E, e, is64);
        int key = (d >> BB) * S + (s >> sshift);
        atomicAdd(&hist[key], 1u);
    }
    __syncthreads();
    for (int u = t; u < NKEY; u += BTHREADS) off[(size_t)u * NBLK + blk] = hist[u];
}

// Scan A: per key, exclusive scan over the 1024 per-block counts.
__global__ __launch_bounds__(BTHREADS) void scan_blocks(
    unsigned int* __restrict__ off, unsigned int* __restrict__ btot) {
    __shared__ unsigned int s[BTHREADS];
    int b = blockIdx.x, t = threadIdx.x;
    unsigned int* row = off + (size_t)b * NBLK;
    unsigned int v0 = row[4 * t], v1 = row[4 * t + 1], v2 = row[4 * t + 2], v3 = row[4 * t + 3];
    unsigned int sum = v0 + v1 + v2 + v3;
    s[t] = sum;
    __syncthreads();
    for (int o = 1; o < BTHREADS; o <<= 1) {
        unsigned int x = (t >= o) ? s[t - o] : 0;
        __syncthreads();
        s[t] += x;
        __syncthreads();
    }
    unsigned int base = t ? s[t - 1] : 0;
    row[4 * t] = base;
    row[4 * t + 1] = base + v0;
    row[4 * t + 2] = base + v0 + v1;
    row[4 * t + 3] = base + v0 + v1 + v2;
    if (t == BTHREADS - 1) btot[b] = s[BTHREADS - 1];
}

// Scan B: exclusive scan over key totals (NKEY <= 2048, 8 per thread) + sentinel.
__global__ __launch_bounds__(BTHREADS) void scan_buckets(
    const unsigned int* __restrict__ btot, unsigned int* __restrict__ bbase, int NKEY) {
    __shared__ unsigned int s[BTHREADS];
    int t = threadIdx.x;
    unsigned int v[8];
    unsigned int sum = 0;
#pragma unroll
    for (int j = 0; j < 8; ++j) {
        int idx = 8 * t + j;
        v[j] = (idx < NKEY) ? btot[idx] : 0;
        sum += v[j];
    }
    s[t] = sum;
    __syncthreads();
    for (int o = 1; o < BTHREADS; o <<= 1) {
        unsigned int x = (t >= o) ? s[t - o] : 0;
        __syncthreads();
        s[t] += x;
        __syncthreads();
    }
    unsigned int base = t ? s[t - 1] : 0;
#pragma unroll
    for (int j = 0; j < 8; ++j) {
        int idx = 8 * t + j;
        if (idx < NKEY) bbase[idx] = base;
        base += v[j];
    }
    if (t == BTHREADS - 1) bbase[NKEY] = s[BTHREADS - 1];  // sentinel = E
}

// Pass 2: scatter packed records (src<<BB | dstlow) into key-contiguous ebin.
__global__ __launch_bounds__(BTHREADS) void pass2_scatter(
    const int* __restrict__ ei, int E, int NKEY, int S, int sshift,
    const unsigned int* __restrict__ off, const unsigned int* __restrict__ bbase,
    unsigned int* __restrict__ ebin) {
    __shared__ unsigned int cur[MAXNB];
    int t = threadIdx.x, blk = blockIdx.x;
    for (int u = t; u < NKEY; u += BTHREADS)
        cur[u] = bbase[u] + off[(size_t)u * NBLK + blk];
    __syncthreads();
    int is64 = detect64(ei);
    int chunk = (E + NBLK - 1) / NBLK;
    int lo = blk * chunk;
    int hi = lo + chunk; if (hi > E) hi = E;
    for (int e = lo + t; e < hi; e += BTHREADS) {
        int s = load_src(ei, e, is64);
        int d = load_dst(ei, E, e, is64);
        int key = (d >> BB) * S + (s >> sshift);
        unsigned int pos = atomicAdd(&cur[key], 1u);
        ebin[pos] = ((unsigned int)s << BB) | (unsigned int)(d & BMASK);
    }
}

// Per bucket (all S slices): degree histogram -> dinv (f32), xs = half4(x*dinv).
__global__ __launch_bounds__(GTHREADS) void deg_prep(
    const unsigned int* __restrict__ ebin, const unsigned int* __restrict__ bbase,
    const float4* __restrict__ x, float* __restrict__ dinv, uint2* __restrict__ xs,
    int N, int S) {
    __shared__ unsigned int dcnt[BSZ];
    int b = blockIdx.x, t = threadIdx.x;
    for (int j = t; j < BSZ; j += GTHREADS) dcnt[j] = 0;
    __syncthreads();
    unsigned int base = bbase[b * S];
    int cnt = (int)(bbase[(b + 1) * S] - base);
    for (int i = t; i < cnt; i += GTHREADS)
        atomicAdd(&dcnt[ebin[base + i] & BMASK], 1u);
    __syncthreads();
    int g0 = b << BB;
    int nn = N - g0; if (nn > BSZ) nn = BSZ;
    for (int j = t; j < nn; j += GTHREADS) {
        int g = g0 + j;
        float di = rsqrtf((float)(dcnt[j] + 1u));
        dinv[g] = di;
        float4 v = x[g];
        uint2 p;
        p.x = h2u(__halves2half2(__float2half_rn(v.x * di), __float2half_rn(v.y * di)));
        p.y = h2u(__halves2half2(__float2half_rn(v.z * di), __float2half_rn(v.w * di)));
        xs[g] = p;
    }
}

// Layer-1 slice gather: block bid = bucket*S + slice. With round-robin XCD
// dispatch, bid%8 pins each XCD to ONE src-slice (2 MB of xs) -> L2-resident
// gathers. Writes dense 32 KB partial per key.
__global__ __launch_bounds__(GTHREADS, 8) void l1_slice(
    const unsigned int* __restrict__ ebin, const unsigned int* __restrict__ bbase,
    const uint2* __restrict__ xs, float4* __restrict__ partial) {
    __shared__ float acc[BSZ][4];   // 32 KB
    int bid = blockIdx.x, t = threadIdx.x;
    {
        float* p = &acc[0][0];
        for (int j = t; j < BSZ * 4; j += GTHREADS) p[j] = 0.0f;
    }
    __syncthreads();
    unsigned int base = bbase[bid];
    int cnt = (int)(bbase[bid + 1] - base);
    for (int i0 = 8 * t; i0 < cnt; i0 += 8 * GTHREADS) {
        int m = cnt - i0; if (m > 8) m = 8;
        unsigned int rec[8];
        uint2 raw[8];
#pragma unroll
        for (int j = 0; j < 8; ++j) if (j < m) rec[j] = ebin[base + i0 + j];
#pragma unroll
        for (int j = 0; j < 8; ++j) if (j < m) raw[j] = xs[rec[j] >> BB];
#pragma unroll
        for (int j = 0; j < 8; ++j) if (j < m) {
            int d = rec[j] & BMASK;
            __half2 h01 = u2h(raw[j].x), h23 = u2h(raw[j].y);
            atomicAdd(&acc[d][0], __half2float(__low2half(h01)));
            atomicAdd(&acc[d][1], __half2float(__high2half(h01)));
            atomicAdd(&acc[d][2], __half2float(__low2half(h23)));
            atomicAdd(&acc[d][3], __half2float(__high2half(h23)));
        }
    }
    __syncthreads();
    size_t pb = (size_t)bid * BSZ;
    for (int j = t; j < BSZ; j += GTHREADS)
        partial[pb + j] = make_float4(acc[j][0], acc[j][1], acc[j][2], acc[j][3]);
}

// Layer-1 reduce (sum S partials) + self-loop + fused MLP -> ps (half2).
__global__ __launch_bounds__(256) void l1_reduce_mlp(
    const float4* __restrict__ partial, const uint2* __restrict__ xs,
    const float* __restrict__ dinv,
    const float* __restrict__ W1, const float* __restrict__ b1,
    const float* __restrict__ W2, unsigned int* __restrict__ ps, int N, int S) {
    __shared__ float sW1[256];
    __shared__ float sb1[64];
    __shared__ float sW2[128];
    int t = threadIdx.x;
    sW1[t] = W1[t];
    if (t < 64) sb1[t] = b1[t];
    if (t < 128) sW2[t] = W2[t];
    __syncthreads();
    int i = blockIdx.x * 256 + t;
    if (i >= N) return;
    int bucket = i >> BB, j = i & BMASK;
    float axs = 0.0f, ays = 0.0f, azs = 0.0f, aws = 0.0f;
    size_t kb = (size_t)bucket * S;
    for (int s = 0; s < S; ++s) {
        float4 v = partial[(kb + s) * BSZ + j];
        axs += v.x; ays += v.y; azs += v.z; aws += v.w;
    }
    float di = dinv[i];
    uint2 raw = xs[i];  // self-loop (quantized, consistent)
    __half2 h01 = u2h(raw.x), h23 = u2h(raw.y);
    float ax = (axs + __half2float(__low2half(h01))) * di;
    float ay = (ays + __half2float(__high2half(h01))) * di;
    float az = (azs + __half2float(__low2half(h23))) * di;
    float aw = (aws + __half2float(__high2half(h23))) * di;
    float p0 = 0.0f, p1 = 0.0f;
#pragma unroll
    for (int k = 0; k < 64; ++k) {
        float h = fmaf(ax, sW1[k],
                  fmaf(ay, sW1[64 + k],
                  fmaf(az, sW1[128 + k],
                  fmaf(aw, sW1[192 + k], sb1[k]))));
        h = fmaxf(h, 0.0f);
        p0 = fmaf(h, sW2[2 * k + 0], p0);
        p1 = fmaf(h, sW2[2 * k + 1], p1);
    }
    ps[i] = h2u(__halves2half2(__float2half_rn(p0 * di), __float2half_rn(p1 * di)));
}

// Layer-2 slice gather: ps table slice (1 MB) is L2-resident per XCD.
__global__ __launch_bounds__(GTHREADS, 8) void l2_slice(
    const unsigned int* __restrict__ ebin, const unsigned int* __restrict__ bbase,
    const unsigned int* __restrict__ ps, float2* __restrict__ partial) {
    __shared__ float acc[BSZ][2];   // 16 KB
    int bid = blockIdx.x, t = threadIdx.x;
    {
        float* p = &acc[0][0];
        for (int j = t; j < BSZ * 2; j += GTHREADS) p[j] = 0.0f;
    }
    __syncthreads();
    unsigned int base = bbase[bid];
    int cnt = (int)(bbase[bid + 1] - base);
    for (int i0 = 8 * t; i0 < cnt; i0 += 8 * GTHREADS) {
        int m = cnt - i0; if (m > 8) m = 8;
        unsigned int rec[8];
        unsigned int raw[8];
#pragma unroll
        for (int j = 0; j < 8; ++j) if (j < m) rec[j] = ebin[base + i0 + j];
#pragma unroll
        for (int j = 0; j < 8; ++j) if (j < m) raw[j] = ps[rec[j] >> BB];
#pragma unroll
        for (int j = 0; j < 8; ++j) if (j < m) {
            int d = rec[j] & BMASK;
            __half2 h = u2h(raw[j]);
            atomicAdd(&acc[d][0], __half2float(__low2half(h)));
            atomicAdd(&acc[d][1], __half2float(__high2half(h)));
        }
    }
    __syncthreads();
    size_t pb = (size_t)bid * BSZ;
    for (int j = t; j < BSZ; j += GTHREADS)
        partial[pb + j] = make_float2(acc[j][0], acc[j][1]);
}

// Layer-2 reduce + self-loop + bias -> out.
__global__ __launch_bounds__(256) void l2_reduce(
    const float2* __restrict__ partial, const unsigned int* __restrict__ ps,
    const float* __restrict__ dinv, const float* __restrict__ b2,
    float2* __restrict__ out, int N, int S) {
    int i = blockIdx.x * 256 + threadIdx.x;
    if (i >= N) return;
    int bucket = i >> BB, j = i & BMASK;
    float s0 = 0.0f, s1 = 0.0f;
    size_t kb = (size_t)bucket * S;
    for (int s = 0; s < S; ++s) {
        float2 v = partial[(kb + s) * BSZ + j];
        s0 += v.x; s1 += v.y;
    }
    float di = dinv[i];
    __half2 h = u2h(ps[i]);  // self-loop
    float2 r;
    r.x = fmaf(s0 + __half2float(__low2half(h)), di, b2[0]);
    r.y = fmaf(s1 + __half2float(__high2half(h)), di, b2[1]);
    out[i] = r;
}

static inline size_t align256(size_t v) { return (v + 255) & ~(size_t)255; }

extern "C" void kernel_launch(void* const* d_in, const int* in_sizes, int n_in,
                              void* d_out, int out_size, void* d_ws, size_t ws_size,
                              hipStream_t stream) {
    const float* x  = (const float*)d_in[0];
    const int*   ei = (const int*)d_in[1];
    const float* W1 = (const float*)d_in[2];
    const float* b1 = (const float*)d_in[3];
    const float* W2 = (const float*)d_in[4];
    const float* b2 = (const float*)d_in[5];

    const int N = in_sizes[0] / 4;
    const int E = in_sizes[1] / 2;
    const int NB = (N + BSZ - 1) >> BB;

    // Choose slice count: S=4 (2 MB xs slice per XCD, L2-resident) if the
    // partial buffer fits the workspace and key count; else S=1 (round-0 path).
    auto compute_need = [&](int S, size_t offs[8]) -> size_t {
        size_t o = 0;
        int NKEY = NB * S;
        offs[0] = o; o = align256(o + (size_t)E * 4);                    // ebin
        offs[1] = o; o = align256(o + (size_t)MAXNB * NBLK * 4);         // off
        offs[2] = o; o = align256(o + (size_t)MAXNB * 4);                // btot
        offs[3] = o; o = align256(o + ((size_t)MAXNB + 1) * 4);          // bbase (+sentinel)
        offs[4] = o; o = align256(o + (size_t)N * 4);                    // dinv
        offs[5] = o; o = align256(o + (size_t)N * 8);                    // xs
        offs[6] = o; o = align256(o + (size_t)N * 4);                    // ps
        offs[7] = o; o = align256(o + (size_t)NKEY * BSZ * 16);          // partial (l2 aliases)
        return o;
    };
    size_t offs[8];
    int S = 4;
    if (NB * 4 > MAXNB || compute_need(4, offs) > ws_size) S = 1;
    compute_need(S, offs);
    const int NKEY = NB * S;
    const int sshift = (S == 4) ? 18 : 20;  // src slice = src >> sshift (N <= 2^20)

    char* ws = (char*)d_ws;
    unsigned int* ebin  = (unsigned int*)(ws + offs[0]);
    unsigned int* off   = (unsigned int*)(ws + offs[1]);
    unsigned int* btot  = (unsigned int*)(ws + offs[2]);
    unsigned int* bbase = (unsigned int*)(ws + offs[3]);
    float*        dinv  = (float*)(ws + offs[4]);
    uint2*        xs    = (uint2*)(ws + offs[5]);
    unsigned int* ps    = (unsigned int*)(ws + offs[6]);
    float4*       part4 = (float4*)(ws + offs[7]);
    float2*       part2 = (float2*)(ws + offs[7]);   // alias: phases are sequential

    pass1_hist<<<NBLK, BTHREADS, 0, stream>>>(ei, E, NKEY, S, sshift, off);
    scan_blocks<<<NKEY, BTHREADS, 0, stream>>>(off, btot);
    scan_buckets<<<1, BTHREADS, 0, stream>>>(btot, bbase, NKEY);
    pass2_scatter<<<NBLK, BTHREADS, 0, stream>>>(ei, E, NKEY, S, sshift, off, bbase, ebin);
    deg_prep<<<NB, GTHREADS, 0, stream>>>(ebin, bbase, (const float4*)x, dinv, xs, N, S);
    l1_slice<<<NKEY, GTHREADS, 0, stream>>>(ebin, bbase, xs, part4);
    l1_reduce_mlp<<<(N + 255) / 256, 256, 0, stream>>>(part4, xs, dinv, W1, b1, W2, ps, N, S);
    l2_slice<<<NKEY, GTHREADS, 0, stream>>>(ebin, bbase, ps, part2);
    l2_reduce<<<(N + 255) / 256, 256, 0, stream>>>(part2, ps, dinv, b2, (float2*)d_out, N, S);
}

// Round 3
// 509.472 us; speedup vs baseline: 1.3228x; 1.2389x over previous
//
#include <hip/hip_runtime.h>
#include <hip/hip_fp16.h>

#define NBLK 1024        // blocks for edge-streaming passes
#define BTHREADS 256
#define BB 11            // bucket bits: 2048 nodes per bucket
#define BSZ (1 << BB)
#define BMASK (BSZ - 1)
#define MAXNB 2048       // max KEYS (= buckets * slices)
#define GTHREADS 512     // sort/prep kernels

// ---------------- helpers ----------------
__device__ __forceinline__ int detect64(const int* __restrict__ ei) {
    return (ei[1] | ei[3] | ei[5] | ei[7] | ei[9] | ei[11] | ei[13] | ei[15]) == 0;
}
__device__ __forceinline__ int load_src(const int* __restrict__ ei, int e, int is64) {
    return is64 ? ei[2 * (size_t)e] : ei[(size_t)e];
}
__device__ __forceinline__ int load_dst(const int* __restrict__ ei, int E, int e, int is64) {
    return is64 ? ei[2 * ((size_t)E + e)] : ei[(size_t)E + e];
}
__device__ __forceinline__ unsigned int h2u(__half2 h) {
    union { __half2 h; unsigned int u; } c; c.h = h; return c.u;
}
__device__ __forceinline__ __half2 u2h(unsigned int u) {
    union { __half2 h; unsigned int u; } c; c.u = u; return c.h;
}

// Pass 1: per-block histogram of (dst-bucket, src-slice) keys. No global atomics.
__global__ __launch_bounds__(BTHREADS) void pass1_hist(
    const int* __restrict__ ei, int E, int NKEY, int S, int sshift,
    unsigned int* __restrict__ off) {
    __shared__ unsigned int hist[MAXNB];
    int t = threadIdx.x, blk = blockIdx.x;
    for (int u = t; u < MAXNB; u += BTHREADS) hist[u] = 0;
    __syncthreads();
    int is64 = detect64(ei);
    int chunk = (E + NBLK - 1) / NBLK;
    int lo = blk * chunk;
    int hi = lo + chunk; if (hi > E) hi = E;
    for (int e = lo + t; e < hi; e += BTHREADS) {
        int s = load_src(ei, e, is64);
        int d = load_dst(ei, E, e, is64);
        int key = (d >> BB) * S + (s >> sshift);
        atomicAdd(&hist[key], 1u);
    }
    __syncthreads();
    for (int u = t; u < NKEY; u += BTHREADS) off[(size_t)u * NBLK + blk] = hist[u];
}

// Scan A: per key, exclusive scan over the 1024 per-block counts.
__global__ __launch_bounds__(BTHREADS) void scan_blocks(
    unsigned int* __restrict__ off, unsigned int* __restrict__ btot) {
    __shared__ unsigned int s[BTHREADS];
    int b = blockIdx.x, t = threadIdx.x;
    unsigned int* row = off + (size_t)b * NBLK;
    unsigned int v0 = row[4 * t], v1 = row[4 * t + 1], v2 = row[4 * t + 2], v3 = row[4 * t + 3];
    unsigned int sum = v0 + v1 + v2 + v3;
    s[t] = sum;
    __syncthreads();
    for (int o = 1; o < BTHREADS; o <<= 1) {
        unsigned int x = (t >= o) ? s[t - o] : 0;
        __syncthreads();
        s[t] += x;
        __syncthreads();
    }
    unsigned int base = t ? s[t - 1] : 0;
    row[4 * t] = base;
    row[4 * t + 1] = base + v0;
    row[4 * t + 2] = base + v0 + v1;
    row[4 * t + 3] = base + v0 + v1 + v2;
    if (t == BTHREADS - 1) btot[b] = s[BTHREADS - 1];
}

// Scan B: exclusive scan over key totals (NKEY <= 2048, 8 per thread) + sentinel.
__global__ __launch_bounds__(BTHREADS) void scan_buckets(
    const unsigned int* __restrict__ btot, unsigned int* __restrict__ bbase, int NKEY) {
    __shared__ unsigned int s[BTHREADS];
    int t = threadIdx.x;
    unsigned int v[8];
    unsigned int sum = 0;
#pragma unroll
    for (int j = 0; j < 8; ++j) {
        int idx = 8 * t + j;
        v[j] = (idx < NKEY) ? btot[idx] : 0;
        sum += v[j];
    }
    s[t] = sum;
    __syncthreads();
    for (int o = 1; o < BTHREADS; o <<= 1) {
        unsigned int x = (t >= o) ? s[t - o] : 0;
        __syncthreads();
        s[t] += x;
        __syncthreads();
    }
    unsigned int base = t ? s[t - 1] : 0;
#pragma unroll
    for (int j = 0; j < 8; ++j) {
        int idx = 8 * t + j;
        if (idx < NKEY) bbase[idx] = base;
        base += v[j];
    }
    if (t == BTHREADS - 1) bbase[NKEY] = s[BTHREADS - 1];  // sentinel = E
}

// Pass 2: scatter packed records (src<<BB | dstlow) into key-contiguous ebin.
__global__ __launch_bounds__(BTHREADS) void pass2_scatter(
    const int* __restrict__ ei, int E, int NKEY, int S, int sshift,
    const unsigned int* __restrict__ off, const unsigned int* __restrict__ bbase,
    unsigned int* __restrict__ ebin) {
    __shared__ unsigned int cur[MAXNB];
    int t = threadIdx.x, blk = blockIdx.x;
    for (int u = t; u < NKEY; u += BTHREADS)
        cur[u] = bbase[u] + off[(size_t)u * NBLK + blk];
    __syncthreads();
    int is64 = detect64(ei);
    int chunk = (E + NBLK - 1) / NBLK;
    int lo = blk * chunk;
    int hi = lo + chunk; if (hi > E) hi = E;
    for (int e = lo + t; e < hi; e += BTHREADS) {
        int s = load_src(ei, e, is64);
        int d = load_dst(ei, E, e, is64);
        int key = (d >> BB) * S + (s >> sshift);
        unsigned int pos = atomicAdd(&cur[key], 1u);
        ebin[pos] = ((unsigned int)s << BB) | (unsigned int)(d & BMASK);
    }
}

// Level-2 sort: per key, sort records by dstlow -> ebin2 (src only),
// and emit u16 row offsets rp16[key*BSZ + j] (exclusive scan of per-node counts).
// Atomics: 2 per edge, banks = d%32 (uniform) -- vs 4/edge on 8 banks before.
// NOTE: assumes per-key edge count < 65536 (random input: ~4090 +/- 64).
__global__ __launch_bounds__(GTHREADS) void sort2(
    const unsigned int* __restrict__ ebin, const unsigned int* __restrict__ bbase,
    unsigned int* __restrict__ ebin2, unsigned short* __restrict__ rp16) {
    __shared__ unsigned int dcnt[BSZ];
    __shared__ unsigned int ssum[GTHREADS];
    int k = blockIdx.x, t = threadIdx.x;
    for (int j = t; j < BSZ; j += GTHREADS) dcnt[j] = 0;
    __syncthreads();
    unsigned int base = bbase[k];
    int cnt = (int)(bbase[k + 1] - base);
    for (int i = t; i < cnt; i += GTHREADS)
        atomicAdd(&dcnt[ebin[base + i] & BMASK], 1u);
    __syncthreads();
    // exclusive scan over 2048 counters, 4 per thread
    unsigned int v0 = dcnt[4 * t], v1 = dcnt[4 * t + 1];
    unsigned int v2 = dcnt[4 * t + 2], v3 = dcnt[4 * t + 3];
    ssum[t] = v0 + v1 + v2 + v3;
    __syncthreads();
    for (int o = 1; o < GTHREADS; o <<= 1) {
        unsigned int x = (t >= o) ? ssum[t - o] : 0;
        __syncthreads();
        ssum[t] += x;
        __syncthreads();
    }
    unsigned int b0 = t ? ssum[t - 1] : 0;
    unsigned int o0 = b0, o1 = b0 + v0, o2 = b0 + v0 + v1, o3 = b0 + v0 + v1 + v2;
    dcnt[4 * t] = o0; dcnt[4 * t + 1] = o1; dcnt[4 * t + 2] = o2; dcnt[4 * t + 3] = o3;
    size_t rbase = (size_t)k * BSZ;
    rp16[rbase + 4 * t]     = (unsigned short)o0;
    rp16[rbase + 4 * t + 1] = (unsigned short)o1;
    rp16[rbase + 4 * t + 2] = (unsigned short)o2;
    rp16[rbase + 4 * t + 3] = (unsigned short)o3;
    __syncthreads();
    for (int i = t; i < cnt; i += GTHREADS) {
        unsigned int rec = ebin[base + i];
        unsigned int pos = atomicAdd(&dcnt[rec & BMASK], 1u);
        ebin2[base + pos] = rec >> BB;   // src node id
    }
}

// Per bucket (all S slices): degree histogram -> dinv (f32), xs = half4(x*dinv).
__global__ __launch_bounds__(GTHREADS) void deg_prep(
    const unsigned int* __restrict__ ebin, const unsigned int* __restrict__ bbase,
    const float4* __restrict__ x, float* __restrict__ dinv, uint2* __restrict__ xs,
    int N, int S) {
    __shared__ unsigned int dcnt[BSZ];
    int b = blockIdx.x, t = threadIdx.x;
    for (int j = t; j < BSZ; j += GTHREADS) dcnt[j] = 0;
    __syncthreads();
    unsigned int base = bbase[b * S];
    int cnt = (int)(bbase[(b + 1) * S] - base);
    for (int i = t; i < cnt; i += GTHREADS)
        atomicAdd(&dcnt[ebin[base + i] & BMASK], 1u);
    __syncthreads();
    int g0 = b << BB;
    int nn = N - g0; if (nn > BSZ) nn = BSZ;
    for (int j = t; j < nn; j += GTHREADS) {
        int g = g0 + j;
        float di = rsqrtf((float)(dcnt[j] + 1u));
        dinv[g] = di;
        float4 v = x[g];
        uint2 p;
        p.x = h2u(__halves2half2(__float2half_rn(v.x * di), __float2half_rn(v.y * di)));
        p.y = h2u(__halves2half2(__float2half_rn(v.z * di), __float2half_rn(v.w * di)));
        xs[g] = p;
    }
}

// Layer-1 gather: thread = (key, node). Atomic-free, LDS-free register
// accumulation over the node's dst-sorted run. xs slice is L2-resident.
__global__ __launch_bounds__(256) void l1_gather(
    const unsigned int* __restrict__ ebin2, const unsigned short* __restrict__ rp16,
    const unsigned int* __restrict__ bbase, const uint2* __restrict__ xs,
    float4* __restrict__ partial, int NKEY) {
    int idx = blockIdx.x * 256 + threadIdx.x;
    if (idx >= NKEY * BSZ) return;
    int k = idx >> BB;
    int j = idx & BMASK;
    unsigned int kb = bbase[k];
    unsigned int st = kb + rp16[idx];
    unsigned int en = (j == BMASK) ? bbase[k + 1] : kb + rp16[idx + 1];
    float ax = 0.0f, ay = 0.0f, az = 0.0f, aw = 0.0f;
    unsigned int e = st;
    for (; e + 2 <= en; e += 2) {            // 2-wide: 2 gathers in flight
        unsigned int s0 = ebin2[e], s1 = ebin2[e + 1];
        uint2 r0 = xs[s0], r1 = xs[s1];
        __half2 a01 = u2h(r0.x), a23 = u2h(r0.y);
        __half2 b01 = u2h(r1.x), b23 = u2h(r1.y);
        ax += __half2float(__low2half(a01)) + __half2float(__low2half(b01));
        ay += __half2float(__high2half(a01)) + __half2float(__high2half(b01));
        az += __half2float(__low2half(a23)) + __half2float(__low2half(b23));
        aw += __half2float(__high2half(a23)) + __half2float(__high2half(b23));
    }
    if (e < en) {
        uint2 r = xs[ebin2[e]];
        __half2 a01 = u2h(r.x), a23 = u2h(r.y);
        ax += __half2float(__low2half(a01));
        ay += __half2float(__high2half(a01));
        az += __half2float(__low2half(a23));
        aw += __half2float(__high2half(a23));
    }
    partial[idx] = make_float4(ax, ay, az, aw);
}

// Layer-1 reduce (sum S partials) + self-loop + fused MLP -> ps (half2).
__global__ __launch_bounds__(256) void l1_reduce_mlp(
    const float4* __restrict__ partial, const uint2* __restrict__ xs,
    const float* __restrict__ dinv,
    const float* __restrict__ W1, const float* __restrict__ b1,
    const float* __restrict__ W2, unsigned int* __restrict__ ps, int N, int S) {
    __shared__ float sW1[256];
    __shared__ float sb1[64];
    __shared__ float sW2[128];
    int t = threadIdx.x;
    sW1[t] = W1[t];
    if (t < 64) sb1[t] = b1[t];
    if (t < 128) sW2[t] = W2[t];
    __syncthreads();
    int i = blockIdx.x * 256 + t;
    if (i >= N) return;
    int bucket = i >> BB, j = i & BMASK;
    float axs = 0.0f, ays = 0.0f, azs = 0.0f, aws = 0.0f;
    size_t kb = (size_t)bucket * S;
    for (int s = 0; s < S; ++s) {
        float4 v = partial[(kb + s) * BSZ + j];
        axs += v.x; ays += v.y; azs += v.z; aws += v.w;
    }
    float di = dinv[i];
    uint2 raw = xs[i];  // self-loop (quantized, consistent)
    __half2 h01 = u2h(raw.x), h23 = u2h(raw.y);
    float ax = (axs + __half2float(__low2half(h01))) * di;
    float ay = (ays + __half2float(__high2half(h01))) * di;
    float az = (azs + __half2float(__low2half(h23))) * di;
    float aw = (aws + __half2float(__high2half(h23))) * di;
    float p0 = 0.0f, p1 = 0.0f;
#pragma unroll
    for (int k = 0; k < 64; ++k) {
        float h = fmaf(ax, sW1[k],
                  fmaf(ay, sW1[64 + k],
                  fmaf(az, sW1[128 + k],
                  fmaf(aw, sW1[192 + k], sb1[k]))));
        h = fmaxf(h, 0.0f);
        p0 = fmaf(h, sW2[2 * k + 0], p0);
        p1 = fmaf(h, sW2[2 * k + 1], p1);
    }
    ps[i] = h2u(__halves2half2(__float2half_rn(p0 * di), __float2half_rn(p1 * di)));
}

// Layer-2 gather: same structure, 2 channels from ps (half2 per node).
__global__ __launch_bounds__(256) void l2_gather(
    const unsigned int* __restrict__ ebin2, const unsigned short* __restrict__ rp16,
    const unsigned int* __restrict__ bbase, const unsigned int* __restrict__ ps,
    float2* __restrict__ partial, int NKEY) {
    int idx = blockIdx.x * 256 + threadIdx.x;
    if (idx >= NKEY * BSZ) return;
    int k = idx >> BB;
    int j = idx & BMASK;
    unsigned int kb = bbase[k];
    unsigned int st = kb + rp16[idx];
    unsigned int en = (j == BMASK) ? bbase[k + 1] : kb + rp16[idx + 1];
    float s0 = 0.0f, s1 = 0.0f;
    unsigned int e = st;
    for (; e + 2 <= en; e += 2) {
        unsigned int a = ebin2[e], b = ebin2[e + 1];
        unsigned int ra = ps[a], rb = ps[b];
        __half2 ha = u2h(ra), hb = u2h(rb);
        s0 += __half2float(__low2half(ha)) + __half2float(__low2half(hb));
        s1 += __half2float(__high2half(ha)) + __half2float(__high2half(hb));
    }
    if (e < en) {
        __half2 h = u2h(ps[ebin2[e]]);
        s0 += __half2float(__low2half(h));
        s1 += __half2float(__high2half(h));
    }
    partial[idx] = make_float2(s0, s1);
}

// Layer-2 reduce + self-loop + bias -> out.
__global__ __launch_bounds__(256) void l2_reduce(
    const float2* __restrict__ partial, const unsigned int* __restrict__ ps,
    const float* __restrict__ dinv, const float* __restrict__ b2,
    float2* __restrict__ out, int N, int S) {
    int i = blockIdx.x * 256 + threadIdx.x;
    if (i >= N) return;
    int bucket = i >> BB, j = i & BMASK;
    float s0 = 0.0f, s1 = 0.0f;
    size_t kb = (size_t)bucket * S;
    for (int s = 0; s < S; ++s) {
        float2 v = partial[(kb + s) * BSZ + j];
        s0 += v.x; s1 += v.y;
    }
    float di = dinv[i];
    __half2 h = u2h(ps[i]);  // self-loop
    float2 r;
    r.x = fmaf(s0 + __half2float(__low2half(h)), di, b2[0]);
    r.y = fmaf(s1 + __half2float(__high2half(h)), di, b2[1]);
    out[i] = r;
}

static inline size_t align256(size_t v) { return (v + 255) & ~(size_t)255; }

extern "C" void kernel_launch(void* const* d_in, const int* in_sizes, int n_in,
                              void* d_out, int out_size, void* d_ws, size_t ws_size,
                              hipStream_t stream) {
    const float* x  = (const float*)d_in[0];
    const int*   ei = (const int*)d_in[1];
    const float* W1 = (const float*)d_in[2];
    const float* b1 = (const float*)d_in[3];
    const float* W2 = (const float*)d_in[4];
    const float* b2 = (const float*)d_in[5];

    const int N = in_sizes[0] / 4;
    const int E = in_sizes[1] / 2;
    const int NB = (N + BSZ - 1) >> BB;

    // offs: 0 ebin, 1 off, 2 btot, 3 bbase, 4 dinv, 5 xs, 6 ps, 7 ebin2, 8 rp16, 9 partial
    auto compute_need = [&](int S, size_t offs[10]) -> size_t {
        size_t o = 0;
        size_t NKEY = (size_t)NB * S;
        offs[0] = o; o = align256(o + (size_t)E * 4);                    // ebin
        offs[1] = o; o = align256(o + (size_t)MAXNB * NBLK * 4);         // off
        offs[2] = o; o = align256(o + (size_t)MAXNB * 4);                // btot
        offs[3] = o; o = align256(o + ((size_t)MAXNB + 1) * 4);          // bbase (+sentinel)
        offs[4] = o; o = align256(o + (size_t)N * 4);                    // dinv
        offs[5] = o; o = align256(o + (size_t)N * 8);                    // xs
        offs[6] = o; o = align256(o + (size_t)N * 4);                    // ps
        offs[7] = o; o = align256(o + (size_t)E * 4);                    // ebin2
        offs[8] = o; o = align256(o + NKEY * BSZ * 2);                   // rp16
        offs[9] = o; o = align256(o + NKEY * BSZ * 16);                  // partial (l2 aliases)
        return o;
    };
    size_t offs[10];
    int S = 1;
    for (int cand = 4; cand >= 1; cand >>= 1) {
        if ((size_t)NB * cand <= MAXNB && compute_need(cand, offs) <= ws_size) { S = cand; break; }
    }
    compute_need(S, offs);
    const int NKEY = NB * S;
    const int sshift = (S == 4) ? 18 : (S == 2) ? 19 : 20;  // src slice (N <= 2^20)

    char* ws = (char*)d_ws;
    unsigned int*   ebin  = (unsigned int*)(ws + offs[0]);
    unsigned int*   off   = (unsigned int*)(ws + offs[1]);
    unsigned int*   btot  = (unsigned int*)(ws + offs[2]);
    unsigned int*   bbase = (unsigned int*)(ws + offs[3]);
    float*          dinv  = (float*)(ws + offs[4]);
    uint2*          xs    = (uint2*)(ws + offs[5]);
    unsigned int*   ps    = (unsigned int*)(ws + offs[6]);
    unsigned int*   ebin2 = (unsigned int*)(ws + offs[7]);
    unsigned short* rp16  = (unsigned short*)(ws + offs[8]);
    float4*         part4 = (float4*)(ws + offs[9]);
    float2*         part2 = (float2*)(ws + offs[9]);   // alias: phases sequential

    const int NODES = NKEY * BSZ;

    pass1_hist<<<NBLK, BTHREADS, 0, stream>>>(ei, E, NKEY, S, sshift, off);
    scan_blocks<<<NKEY, BTHREADS, 0, stream>>>(off, btot);
    scan_buckets<<<1, BTHREADS, 0, stream>>>(btot, bbase, NKEY);
    pass2_scatter<<<NBLK, BTHREADS, 0, stream>>>(ei, E, NKEY, S, sshift, off, bbase, ebin);
    sort2<<<NKEY, GTHREADS, 0, stream>>>(ebin, bbase, ebin2, rp16);
    deg_prep<<<NB, GTHREADS, 0, stream>>>(ebin, bbase, (const float4*)x, dinv, xs, N, S);
    l1_gather<<<(NODES + 255) / 256, 256, 0, stream>>>(ebin2, rp16, bbase, xs, part4, NKEY);
    l1_reduce_mlp<<<(N + 255) / 256, 256, 0, stream>>>(part4, xs, dinv, W1, b1, W2, ps, N, S);
    l2_gather<<<(NODES + 255) / 256, 256, 0, stream>>>(ebin2, rp16, bbase, ps, part2, NKEY);
    l2_reduce<<<(N + 255) / 256, 256, 0, stream>>>(part2, ps, dinv, b2, (float2*)d_out, N, S);
}

// Round 4
// 495.015 us; speedup vs baseline: 1.3614x; 1.0292x over previous
//
#include <hip/hip_runtime.h>
#include <hip/hip_fp16.h>

#define NBLK 1024        // blocks for edge-streaming passes
#define BTHREADS 256
#define BB 11            // bucket bits: 2048 nodes per bucket
#define BSZ (1 << BB)
#define BMASK (BSZ - 1)
#define MAXNB 512        // max dst-buckets (N <= 1,048,576)
#define SLICES 4         // src slices (xs slice = 2 MB -> per-XCD L2-resident)
#define SSHIFT 18        // src slice = src >> 18 (N <= 2^20)
#define SKEYS (SLICES * BSZ)   // 8192 13-bit sort keys per bucket
#define GTHREADS 512
#define CP(i) ((i) + ((i) >> 5))   // +1-per-32 pad: breaks LDS bank conflicts

// ---------------- helpers ----------------
__device__ __forceinline__ int detect64(const int* __restrict__ ei) {
    return (ei[1] | ei[3] | ei[5] | ei[7] | ei[9] | ei[11] | ei[13] | ei[15]) == 0;
}
__device__ __forceinline__ int load_src(const int* __restrict__ ei, int e, int is64) {
    return is64 ? ei[2 * (size_t)e] : ei[(size_t)e];
}
__device__ __forceinline__ int load_dst(const int* __restrict__ ei, int E, int e, int is64) {
    return is64 ? ei[2 * ((size_t)E + e)] : ei[(size_t)E + e];
}
__device__ __forceinline__ unsigned int h2u(__half2 h) {
    union { __half2 h; unsigned int u; } c; c.h = h; return c.u;
}
__device__ __forceinline__ __half2 u2h(unsigned int u) {
    union { __half2 h; unsigned int u; } c; c.u = u; return c.h;
}

// Pass 1: per-block histogram of dst-buckets (dst-only read: 64 MB not 128).
__global__ __launch_bounds__(BTHREADS) void pass1_hist(
    const int* __restrict__ ei, int E, int NB, unsigned int* __restrict__ off) {
    __shared__ unsigned int hist[MAXNB];
    int t = threadIdx.x, blk = blockIdx.x;
    for (int u = t; u < MAXNB; u += BTHREADS) hist[u] = 0;
    __syncthreads();
    int is64 = detect64(ei);
    int chunk = (E + NBLK - 1) / NBLK;
    int lo = blk * chunk;
    int hi = lo + chunk; if (hi > E) hi = E;
    for (int e = lo + t; e < hi; e += BTHREADS) {
        int d = load_dst(ei, E, e, is64);
        atomicAdd(&hist[d >> BB], 1u);
    }
    __syncthreads();
    for (int u = t; u < NB; u += BTHREADS) off[(size_t)u * NBLK + blk] = hist[u];
}

// Scan A: per bucket, exclusive scan over the 1024 per-block counts.
__global__ __launch_bounds__(BTHREADS) void scan_blocks(
    unsigned int* __restrict__ off, unsigned int* __restrict__ btot) {
    __shared__ unsigned int s[BTHREADS];
    int b = blockIdx.x, t = threadIdx.x;
    unsigned int* row = off + (size_t)b * NBLK;
    unsigned int v0 = row[4 * t], v1 = row[4 * t + 1], v2 = row[4 * t + 2], v3 = row[4 * t + 3];
    unsigned int sum = v0 + v1 + v2 + v3;
    s[t] = sum;
    __syncthreads();
    for (int o = 1; o < BTHREADS; o <<= 1) {
        unsigned int x = (t >= o) ? s[t - o] : 0;
        __syncthreads();
        s[t] += x;
        __syncthreads();
    }
    unsigned int base = t ? s[t - 1] : 0;
    row[4 * t] = base;
    row[4 * t + 1] = base + v0;
    row[4 * t + 2] = base + v0 + v1;
    row[4 * t + 3] = base + v0 + v1 + v2;
    if (t == BTHREADS - 1) btot[b] = s[BTHREADS - 1];
}

// Scan B: exclusive scan over bucket totals (NB <= 512) + sentinel = E.
__global__ __launch_bounds__(BTHREADS) void scan_buckets(
    const unsigned int* __restrict__ btot, unsigned int* __restrict__ bktbase, int NB) {
    __shared__ unsigned int s[BTHREADS];
    int t = threadIdx.x;
    unsigned int v[8];
    unsigned int sum = 0;
#pragma unroll
    for (int j = 0; j < 8; ++j) {
        int idx = 8 * t + j;
        v[j] = (idx < NB) ? btot[idx] : 0;
        sum += v[j];
    }
    s[t] = sum;
    __syncthreads();
    for (int o = 1; o < BTHREADS; o <<= 1) {
        unsigned int x = (t >= o) ? s[t - o] : 0;
        __syncthreads();
        s[t] += x;
        __syncthreads();
    }
    unsigned int base = t ? s[t - 1] : 0;
#pragma unroll
    for (int j = 0; j < 8; ++j) {
        int idx = 8 * t + j;
        if (idx < NB) bktbase[idx] = base;
        base += v[j];
    }
    if (t == BTHREADS - 1) bktbase[NB] = s[BTHREADS - 1];  // sentinel = E
}

// Pass 2: scatter packed records (src<<BB | dstlow) into bucket-contiguous ebin.
// Bucket-only keys (489): per-block runs are ~16 records = 64 B -> low write amp.
__global__ __launch_bounds__(BTHREADS) void pass2_scatter(
    const int* __restrict__ ei, int E, int NB,
    const unsigned int* __restrict__ off, const unsigned int* __restrict__ bktbase,
    unsigned int* __restrict__ ebin) {
    __shared__ unsigned int cur[MAXNB];
    int t = threadIdx.x, blk = blockIdx.x;
    for (int u = t; u < NB; u += BTHREADS)
        cur[u] = bktbase[u] + off[(size_t)u * NBLK + blk];
    __syncthreads();
    int is64 = detect64(ei);
    int chunk = (E + NBLK - 1) / NBLK;
    int lo = blk * chunk;
    int hi = lo + chunk; if (hi > E) hi = E;
    for (int e = lo + t; e < hi; e += BTHREADS) {
        int s = load_src(ei, e, is64);
        int d = load_dst(ei, E, e, is64);
        unsigned int pos = atomicAdd(&cur[d >> BB], 1u);
        ebin[pos] = ((unsigned int)s << BB) | (unsigned int)(d & BMASK);
    }
}

// Per bucket: 13-bit counting sort by (srcslice<<11 | dstlow) -> ebin2 (src ids),
// u16 row offsets rp16 (relative to bucket base), AND degree->dinv->xs prep.
__global__ __launch_bounds__(GTHREADS) void sort2_deg(
    const unsigned int* __restrict__ ebin, const unsigned int* __restrict__ bktbase,
    const float4* __restrict__ x, float* __restrict__ dinv, uint2* __restrict__ xs,
    unsigned int* __restrict__ ebin2, unsigned short* __restrict__ rp16, int N) {
    __shared__ unsigned int cnt[CP(SKEYS)];   // ~33 KB, bank-padded
    __shared__ unsigned int ssum[GTHREADS];
    int b = blockIdx.x, t = threadIdx.x;
    for (int j = t; j < CP(SKEYS); j += GTHREADS) cnt[j] = 0;
    __syncthreads();
    unsigned int base = bktbase[b];
    int ne = (int)(bktbase[b + 1] - base);
    for (int i = t; i < ne; i += GTHREADS) {
        unsigned int rec = ebin[base + i];
        unsigned int k13 = ((rec >> (BB + SSHIFT)) << BB) | (rec & BMASK);
        atomicAdd(&cnt[CP(k13)], 1u);
    }
    __syncthreads();
    // degree (sum over 4 slices) -> dinv + quantized scaled features
    int g0 = b << BB;
    int nn = N - g0; if (nn > BSZ) nn = BSZ;
    for (int j = t; j < nn; j += GTHREADS) {
        unsigned int deg = cnt[CP(j)] + cnt[CP(BSZ + j)] + cnt[CP(2 * BSZ + j)] + cnt[CP(3 * BSZ + j)];
        int g = g0 + j;
        float di = rsqrtf((float)(deg + 1u));
        dinv[g] = di;
        float4 v = x[g];
        uint2 p;
        p.x = h2u(__halves2half2(__float2half_rn(v.x * di), __float2half_rn(v.y * di)));
        p.y = h2u(__halves2half2(__float2half_rn(v.z * di), __float2half_rn(v.w * di)));
        xs[g] = p;
    }
    // exclusive scan of 8192 counters: 16 contiguous per thread + block scan
    unsigned int loc[16];
    unsigned int s = 0;
#pragma unroll
    for (int j = 0; j < 16; ++j) { loc[j] = s; s += cnt[CP(16 * t + j)]; }
    ssum[t] = s;
    __syncthreads();
    for (int o = 1; o < GTHREADS; o <<= 1) {
        unsigned int v = (t >= o) ? ssum[t - o] : 0;
        __syncthreads();
        ssum[t] += v;
        __syncthreads();
    }
    unsigned int tb = t ? ssum[t - 1] : 0;
    size_t rb = (size_t)b * SKEYS;
#pragma unroll
    for (int j = 0; j < 16; ++j)
        rp16[rb + 16 * t + j] = (unsigned short)(tb + loc[j]);
#pragma unroll
    for (int j = 0; j < 16; ++j) cnt[CP(16 * t + j)] = tb + loc[j];
    __syncthreads();
    // scatter src ids into sorted order (L2-local: 64 KB bucket range)
    for (int i = t; i < ne; i += GTHREADS) {
        unsigned int rec = ebin[base + i];
        unsigned int k13 = ((rec >> (BB + SSHIFT)) << BB) | (rec & BMASK);
        unsigned int pos = atomicAdd(&cnt[CP(k13)], 1u);
        ebin2[base + pos] = rec >> BB;   // src node id
    }
}

// Block remap: bid%8 determines XCD (round-robin dispatch); pin slice = (bid&3)
// so each XCD's gather working set is ONE 2 MB slice (round-2-proven mapping).
// bid in [0, NB*32): r=bid&7 -> s=r&3, half=r>>2; q=bid>>3 -> b=q>>2, sub=half*4+(q&3).
__global__ __launch_bounds__(256) void l1_gather(
    const unsigned int* __restrict__ ebin2, const unsigned short* __restrict__ rp16,
    const unsigned int* __restrict__ bktbase, const uint2* __restrict__ xs,
    float4* __restrict__ partial) {
    int bid = blockIdx.x, t = threadIdx.x;
    int r = bid & 7, s = r & 3, half = r >> 2, q = bid >> 3;
    int b = q >> 2, sub = (half << 2) | (q & 3);
    int idx = (((b << 2) + s) << BB) + (sub << 8) + t;
    unsigned int kb = bktbase[b];
    unsigned int st = kb + rp16[idx];
    bool last = (s == SLICES - 1) && (sub == 7) && (t == 255);
    unsigned int en = last ? bktbase[b + 1] : kb + rp16[idx + 1];
    float ax = 0.0f, ay = 0.0f, az = 0.0f, aw = 0.0f;
    unsigned int e = st;
    for (; e + 2 <= en; e += 2) {
        unsigned int s0 = ebin2[e], s1 = ebin2[e + 1];
        uint2 r0 = xs[s0], r1 = xs[s1];
        __half2 a01 = u2h(r0.x), a23 = u2h(r0.y);
        __half2 b01 = u2h(r1.x), b23 = u2h(r1.y);
        ax += __half2float(__low2half(a01)) + __half2float(__low2half(b01));
        ay += __half2float(__high2half(a01)) + __half2float(__high2half(b01));
        az += __half2float(__low2half(a23)) + __half2float(__low2half(b23));
        aw += __half2float(__high2half(a23)) + __half2float(__high2half(b23));
    }
    if (e < en) {
        uint2 rr = xs[ebin2[e]];
        __half2 a01 = u2h(rr.x), a23 = u2h(rr.y);
        ax += __half2float(__low2half(a01));
        ay += __half2float(__high2half(a01));
        az += __half2float(__low2half(a23));
        aw += __half2float(__high2half(a23));
    }
    partial[idx] = make_float4(ax, ay, az, aw);
}

// Layer-1 reduce (sum 4 slice partials) + self-loop + fused MLP -> ps (half2).
__global__ __launch_bounds__(256) void l1_reduce_mlp(
    const float4* __restrict__ partial, const uint2* __restrict__ xs,
    const float* __restrict__ dinv,
    const float* __restrict__ W1, const float* __restrict__ b1,
    const float* __restrict__ W2, unsigned int* __restrict__ ps, int N) {
    __shared__ float sW1[256];
    __shared__ float sb1[64];
    __shared__ float sW2[128];
    int t = threadIdx.x;
    sW1[t] = W1[t];
    if (t < 64) sb1[t] = b1[t];
    if (t < 128) sW2[t] = W2[t];
    __syncthreads();
    int i = blockIdx.x * 256 + t;
    if (i >= N) return;
    int bucket = i >> BB, j = i & BMASK;
    float axs = 0.0f, ays = 0.0f, azs = 0.0f, aws = 0.0f;
    size_t kb = (size_t)bucket * SLICES;
    for (int s = 0; s < SLICES; ++s) {
        float4 v = partial[(kb + s) * BSZ + j];
        axs += v.x; ays += v.y; azs += v.z; aws += v.w;
    }
    float di = dinv[i];
    uint2 raw = xs[i];  // self-loop (quantized, consistent)
    __half2 h01 = u2h(raw.x), h23 = u2h(raw.y);
    float ax = (axs + __half2float(__low2half(h01))) * di;
    float ay = (ays + __half2float(__high2half(h01))) * di;
    float az = (azs + __half2float(__low2half(h23))) * di;
    float aw = (aws + __half2float(__high2half(h23))) * di;
    float p0 = 0.0f, p1 = 0.0f;
#pragma unroll
    for (int k = 0; k < 64; ++k) {
        float h = fmaf(ax, sW1[k],
                  fmaf(ay, sW1[64 + k],
                  fmaf(az, sW1[128 + k],
                  fmaf(aw, sW1[192 + k], sb1[k]))));
        h = fmaxf(h, 0.0f);
        p0 = fmaf(h, sW2[2 * k + 0], p0);
        p1 = fmaf(h, sW2[2 * k + 1], p1);
    }
    ps[i] = h2u(__halves2half2(__float2half_rn(p0 * di), __float2half_rn(p1 * di)));
}

// Layer-2 gather: same XCD-pinned mapping; ps slice (1 MB) is L2-resident.
__global__ __launch_bounds__(256) void l2_gather(
    const unsigned int* __restrict__ ebin2, const unsigned short* __restrict__ rp16,
    const unsigned int* __restrict__ bktbase, const unsigned int* __restrict__ ps,
    float2* __restrict__ partial) {
    int bid = blockIdx.x, t = threadIdx.x;
    int r = bid & 7, s = r & 3, half = r >> 2, q = bid >> 3;
    int b = q >> 2, sub = (half << 2) | (q & 3);
    int idx = (((b << 2) + s) << BB) + (sub << 8) + t;
    unsigned int kb = bktbase[b];
    unsigned int st = kb + rp16[idx];
    bool last = (s == SLICES - 1) && (sub == 7) && (t == 255);
    unsigned int en = last ? bktbase[b + 1] : kb + rp16[idx + 1];
    float s0 = 0.0f, s1 = 0.0f;
    unsigned int e = st;
    for (; e + 2 <= en; e += 2) {
        unsigned int a = ebin2[e], bb = ebin2[e + 1];
        unsigned int ra = ps[a], rb2 = ps[bb];
        __half2 ha = u2h(ra), hb = u2h(rb2);
        s0 += __half2float(__low2half(ha)) + __half2float(__low2half(hb));
        s1 += __half2float(__high2half(ha)) + __half2float(__high2half(hb));
    }
    if (e < en) {
        __half2 h = u2h(ps[ebin2[e]]);
        s0 += __half2float(__low2half(h));
        s1 += __half2float(__high2half(h));
    }
    partial[idx] = make_float2(s0, s1);
}

// Layer-2 reduce + self-loop + bias -> out.
__global__ __launch_bounds__(256) void l2_reduce(
    const float2* __restrict__ partial, const unsigned int* __restrict__ ps,
    const float* __restrict__ dinv, const float* __restrict__ b2,
    float2* __restrict__ out, int N) {
    int i = blockIdx.x * 256 + threadIdx.x;
    if (i >= N) return;
    int bucket = i >> BB, j = i & BMASK;
    float s0 = 0.0f, s1 = 0.0f;
    size_t kb = (size_t)bucket * SLICES;
    for (int s = 0; s < SLICES; ++s) {
        float2 v = partial[(kb + s) * BSZ + j];
        s0 += v.x; s1 += v.y;
    }
    float di = dinv[i];
    __half2 h = u2h(ps[i]);  // self-loop
    float2 rr;
    rr.x = fmaf(s0 + __half2float(__low2half(h)), di, b2[0]);
    rr.y = fmaf(s1 + __half2float(__high2half(h)), di, b2[1]);
    out[i] = rr;
}

static inline size_t align256(size_t v) { return (v + 255) & ~(size_t)255; }

extern "C" void kernel_launch(void* const* d_in, const int* in_sizes, int n_in,
                              void* d_out, int out_size, void* d_ws, size_t ws_size,
                              hipStream_t stream) {
    const float* x  = (const float*)d_in[0];
    const int*   ei = (const int*)d_in[1];
    const float* W1 = (const float*)d_in[2];
    const float* b1 = (const float*)d_in[3];
    const float* W2 = (const float*)d_in[4];
    const float* b2 = (const float*)d_in[5];

    const int N = in_sizes[0] / 4;
    const int E = in_sizes[1] / 2;
    const int NB = (N + BSZ - 1) >> BB;

    // Persistent buffers, then region R where partial ALIASES {ebin, off, btot}
    // (ebin/off/btot are dead before l1_gather writes partial).
    size_t o = 0;
    size_t o_bkt  = o; o = align256(o + ((size_t)MAXNB + 1) * 4);          // bktbase
    size_t o_dinv = o; o = align256(o + (size_t)N * 4);                    // dinv
    size_t o_xs   = o; o = align256(o + (size_t)N * 8);                    // xs
    size_t o_ps   = o; o = align256(o + (size_t)N * 4);                    // ps
    size_t o_eb2  = o; o = align256(o + (size_t)E * 4);                    // ebin2
    size_t o_rp   = o; o = align256(o + (size_t)NB * SKEYS * 2);           // rp16
    size_t o_R    = o;                                                     // region R
    size_t o_ebin = o_R;
    size_t o_off  = align256(o_ebin + (size_t)E * 4);
    size_t o_btot = align256(o_off + (size_t)MAXNB * NBLK * 4);

    char* ws = (char*)d_ws;
    unsigned int*   bktbase = (unsigned int*)(ws + o_bkt);
    float*          dinv    = (float*)(ws + o_dinv);
    uint2*          xs      = (uint2*)(ws + o_xs);
    unsigned int*   ps      = (unsigned int*)(ws + o_ps);
    unsigned int*   ebin2   = (unsigned int*)(ws + o_eb2);
    unsigned short* rp16    = (unsigned short*)(ws + o_rp);
    unsigned int*   ebin    = (unsigned int*)(ws + o_ebin);
    unsigned int*   off     = (unsigned int*)(ws + o_off);
    unsigned int*   btot    = (unsigned int*)(ws + o_btot);
    float4*         part4   = (float4*)(ws + o_R);   // aliases ebin/off/btot
    float2*         part2   = (float2*)(ws + o_R);   // sequential phases

    pass1_hist<<<NBLK, BTHREADS, 0, stream>>>(ei, E, NB, off);
    scan_blocks<<<NB, BTHREADS, 0, stream>>>(off, btot);
    scan_buckets<<<1, BTHREADS, 0, stream>>>(btot, bktbase, NB);
    pass2_scatter<<<NBLK, BTHREADS, 0, stream>>>(ei, E, NB, off, bktbase, ebin);
    sort2_deg<<<NB, GTHREADS, 0, stream>>>(ebin, bktbase, (const float4*)x, dinv, xs, ebin2, rp16, N);
    l1_gather<<<NB * 32, 256, 0, stream>>>(ebin2, rp16, bktbase, xs, part4);
    l1_reduce_mlp<<<(N + 255) / 256, 256, 0, stream>>>(part4, xs, dinv, W1, b1, W2, ps, N);
    l2_gather<<<NB * 32, 256, 0, stream>>>(ebin2, rp16, bktbase, ps, part2);
    l2_reduce<<<(N + 255) / 256, 256, 0, stream>>>(part2, ps, dinv, b2, (float2*)d_out, N);
}

// Round 6
// 492.813 us; speedup vs baseline: 1.3675x; 1.0045x over previous
//
#include <hip/hip_runtime.h>
#include <hip/hip_fp16.h>

#define BTHREADS 256
#define CHUNK 7936       // edges per local_sort block (31 KB LDS staging)
#define BB 11            // bucket bits: 2048 nodes per bucket
#define BSZ (1 << BB)
#define BMASK (BSZ - 1)
#define MAXNB 512        // max dst-buckets (N <= 1,048,576)
#define SLICES 4         // src slices (xs slice = 2 MB -> per-XCD L2-resident)
#define SSHIFT 18        // src slice = src >> 18 (N <= 2^20)
#define SKEYS (SLICES * BSZ)   // 8192 13-bit sort keys per bucket
#define GTHREADS 512
#define CP(i) ((i) + ((i) >> 5))   // +1-per-32 pad: breaks LDS bank conflicts

// ---------------- helpers ----------------
__device__ __forceinline__ int detect64(const int* __restrict__ ei) {
    return (ei[1] | ei[3] | ei[5] | ei[7] | ei[9] | ei[11] | ei[13] | ei[15]) == 0;
}
__device__ __forceinline__ int load_src(const int* __restrict__ ei, int e, int is64) {
    return is64 ? ei[2 * (size_t)e] : ei[(size_t)e];
}
__device__ __forceinline__ int load_dst(const int* __restrict__ ei, int E, int e, int is64) {
    return is64 ? ei[2 * ((size_t)E + e)] : ei[(size_t)E + e];
}
__device__ __forceinline__ unsigned int h2u(__half2 h) {
    union { __half2 h; unsigned int u; } c; c.h = h; return c.u;
}
__device__ __forceinline__ __half2 u2h(unsigned int u) {
    union { __half2 h; unsigned int u; } c; c.u = u; return c.h;
}

// local_sort: per chunk of CHUNK edges -- LDS histogram over dst-buckets,
// LDS exclusive scan, LDS scatter (bucket-sorted), then CONTIGUOUS flush to
// stage[blk*CHUNK] (write amp 1.0; no scattered global stores anywhere).
// Writes lofs[blk][b] = within-chunk exclusive offsets (lofs[blk][NB] = n).
__global__ __launch_bounds__(BTHREADS) void local_sort(
    const int* __restrict__ ei, int E, int NB,
    unsigned int* __restrict__ lofs, unsigned int* __restrict__ stage) {
    __shared__ unsigned int cnt[MAXNB + 1];
    __shared__ unsigned int ssum[BTHREADS];
    __shared__ unsigned int stg[CHUNK];   // 31 KB
    int t = threadIdx.x, blk = blockIdx.x;
    int NB1 = NB + 1;
    for (int u = t; u <= NB; u += BTHREADS) cnt[u] = 0;
    __syncthreads();
    int is64 = detect64(ei);
    int lo = blk * CHUNK;
    int hi = lo + CHUNK; if (hi > E) hi = E;
    int n = hi - lo;
    for (int e = lo + t; e < hi; e += BTHREADS) {
        int d = load_dst(ei, E, e, is64);
        atomicAdd(&cnt[d >> BB], 1u);
    }
    __syncthreads();
    // exclusive scan over NB counters (2 per thread, NB <= 512)
    unsigned int v0 = (2 * t < NB) ? cnt[2 * t] : 0;
    unsigned int v1 = (2 * t + 1 < NB) ? cnt[2 * t + 1] : 0;
    ssum[t] = v0 + v1;
    __syncthreads();
    for (int o = 1; o < BTHREADS; o <<= 1) {
        unsigned int x2 = (t >= o) ? ssum[t - o] : 0;
        __syncthreads();
        ssum[t] += x2;
        __syncthreads();
    }
    unsigned int base = t ? ssum[t - 1] : 0;
    size_t lb = (size_t)blk * NB1;
    if (2 * t < NB)     { lofs[lb + 2 * t]     = base;      cnt[2 * t]     = base; }
    if (2 * t + 1 < NB) { lofs[lb + 2 * t + 1] = base + v0; cnt[2 * t + 1] = base + v0; }
    if (t == 0) lofs[lb + NB] = (unsigned int)n;
    __syncthreads();
    // scatter into LDS staging (LDS absorbs the scatter at bank granularity)
    for (int e = lo + t; e < hi; e += BTHREADS) {
        int s = load_src(ei, e, is64);
        int d = load_dst(ei, E, e, is64);
        unsigned int pos = atomicAdd(&cnt[d >> BB], 1u);
        stg[pos] = ((unsigned int)s << BB) | (unsigned int)(d & BMASK);
    }
    __syncthreads();
    // contiguous coalesced flush
    unsigned int* sg = stage + (size_t)blk * CHUNK;
    for (int j = t; j < n; j += BTHREADS) sg[j] = stg[j];
}

// bktbase[b] = sum over blk of lofs[blk][b]  (telescoping: the row-sum of the
// within-chunk exclusive offsets IS the global exclusive bucket base).
__global__ __launch_bounds__(BTHREADS) void rowsum(
    const unsigned int* __restrict__ lofs, unsigned int* __restrict__ bktbase,
    int NBLKr, int NB1) {
    __shared__ unsigned int red[BTHREADS];
    int b = blockIdx.x, t = threadIdx.x;
    unsigned int s = 0;
    for (int blk = t; blk < NBLKr; blk += BTHREADS)
        s += lofs[(size_t)blk * NB1 + b];
    red[t] = s;
    __syncthreads();
    for (int o = BTHREADS / 2; o > 0; o >>= 1) {
        if (t < o) red[t] += red[t + o];
        __syncthreads();
    }
    if (t == 0) bktbase[b] = red[0];
}

// Per bucket: read the bucket's runs from all chunks of stage (small scattered
// READS, L2/L3-hot), 13-bit counting sort by (srcslice<<11 | dstlow) -> ebin2
// (src ids), u16 row offsets rp16, AND degree->dinv->xs prep.
__global__ __launch_bounds__(GTHREADS) void sort2_deg(
    const unsigned int* __restrict__ stage, const unsigned int* __restrict__ lofs,
    const unsigned int* __restrict__ bktbase,
    const float4* __restrict__ x, float* __restrict__ dinv, uint2* __restrict__ xs,
    unsigned int* __restrict__ ebin2, unsigned short* __restrict__ rp16,
    int N, int NBLKr, int NB) {
    __shared__ unsigned int cnt[CP(SKEYS)];   // ~33 KB, bank-padded
    __shared__ unsigned int ssum[GTHREADS];
    int b = blockIdx.x, t = threadIdx.x;
    int NB1 = NB + 1;
    for (int j = t; j < CP(SKEYS); j += GTHREADS) cnt[j] = 0;
    __syncthreads();
    // count phase: iterate this bucket's run within every chunk
    for (int blk = t; blk < NBLKr; blk += GTHREADS) {
        size_t lb = (size_t)blk * NB1;
        unsigned int st = lofs[lb + b], en = lofs[lb + b + 1];
        const unsigned int* sg = stage + (size_t)blk * CHUNK;
        for (unsigned int i = st; i < en; ++i) {
            unsigned int rec = sg[i];
            unsigned int k13 = ((rec >> (BB + SSHIFT)) << BB) | (rec & BMASK);
            atomicAdd(&cnt[CP(k13)], 1u);
        }
    }
    __syncthreads();
    // degree (sum over 4 slices) -> dinv + quantized scaled features
    int g0 = b << BB;
    int nn = N - g0; if (nn > BSZ) nn = BSZ;
    for (int j = t; j < nn; j += GTHREADS) {
        unsigned int deg = cnt[CP(j)] + cnt[CP(BSZ + j)] + cnt[CP(2 * BSZ + j)] + cnt[CP(3 * BSZ + j)];
        int g = g0 + j;
        float di = rsqrtf((float)(deg + 1u));
        dinv[g] = di;
        float4 v = x[g];
        uint2 p;
        p.x = h2u(__halves2half2(__float2half_rn(v.x * di), __float2half_rn(v.y * di)));
        p.y = h2u(__halves2half2(__float2half_rn(v.z * di), __float2half_rn(v.w * di)));
        xs[g] = p;
    }
    // exclusive scan of 8192 counters: 16 contiguous per thread + block scan
    unsigned int loc[16];
    unsigned int s = 0;
#pragma unroll
    for (int j = 0; j < 16; ++j) { loc[j] = s; s += cnt[CP(16 * t + j)]; }
    ssum[t] = s;
    __syncthreads();
    for (int o = 1; o < GTHREADS; o <<= 1) {
        unsigned int v = (t >= o) ? ssum[t - o] : 0;
        __syncthreads();
        ssum[t] += v;
        __syncthreads();
    }
    unsigned int tb = t ? ssum[t - 1] : 0;
    size_t rb = (size_t)b * SKEYS;
#pragma unroll
    for (int j = 0; j < 16; ++j)
        rp16[rb + 16 * t + j] = (unsigned short)(tb + loc[j]);
#pragma unroll
    for (int j = 0; j < 16; ++j) cnt[CP(16 * t + j)] = tb + loc[j];
    __syncthreads();
    // scatter src ids into sorted order (bucket-local 64 KB range: L2-resident)
    unsigned int base = bktbase[b];
    for (int blk = t; blk < NBLKr; blk += GTHREADS) {
        size_t lb = (size_t)blk * NB1;
        unsigned int st = lofs[lb + b], en = lofs[lb + b + 1];
        const unsigned int* sg = stage + (size_t)blk * CHUNK;
        for (unsigned int i = st; i < en; ++i) {
            unsigned int rec = sg[i];
            unsigned int k13 = ((rec >> (BB + SSHIFT)) << BB) | (rec & BMASK);
            unsigned int pos = atomicAdd(&cnt[CP(k13)], 1u);
            ebin2[base + pos] = rec >> BB;   // src node id
        }
    }
}

// Block remap: bid%8 determines XCD (round-robin dispatch); pin slice = (bid&3)
// so each XCD's gather working set is ONE 2 MB slice (round-2-proven mapping).
__global__ __launch_bounds__(256) void l1_gather(
    const unsigned int* __restrict__ ebin2, const unsigned short* __restrict__ rp16,
    const unsigned int* __restrict__ bktbase, const uint2* __restrict__ xs,
    float4* __restrict__ partial) {
    int bid = blockIdx.x, t = threadIdx.x;
    int r = bid & 7, s = r & 3, half = r >> 2, q = bid >> 3;
    int b = q >> 2, sub = (half << 2) | (q & 3);
    int idx = (((b << 2) + s) << BB) + (sub << 8) + t;
    unsigned int kb = bktbase[b];
    unsigned int st = kb + rp16[idx];
    bool last = (s == SLICES - 1) && (sub == 7) && (t == 255);
    unsigned int en = last ? bktbase[b + 1] : kb + rp16[idx + 1];
    float ax = 0.0f, ay = 0.0f, az = 0.0f, aw = 0.0f;
    unsigned int e = st;
    for (; e + 2 <= en; e += 2) {
        unsigned int s0 = ebin2[e], s1 = ebin2[e + 1];
        uint2 r0 = xs[s0], r1 = xs[s1];
        __half2 a01 = u2h(r0.x), a23 = u2h(r0.y);
        __half2 b01 = u2h(r1.x), b23 = u2h(r1.y);
        ax += __half2float(__low2half(a01)) + __half2float(__low2half(b01));
        ay += __half2float(__high2half(a01)) + __half2float(__high2half(b01));
        az += __half2float(__low2half(a23)) + __half2float(__low2half(b23));
        aw += __half2float(__high2half(a23)) + __half2float(__high2half(b23));
    }
    if (e < en) {
        uint2 rr = xs[ebin2[e]];
        __half2 a01 = u2h(rr.x), a23 = u2h(rr.y);
        ax += __half2float(__low2half(a01));
        ay += __half2float(__high2half(a01));
        az += __half2float(__low2half(a23));
        aw += __half2float(__high2half(a23));
    }
    partial[idx] = make_float4(ax, ay, az, aw);
}

// Layer-1 reduce (sum 4 slice partials) + self-loop + fused MLP -> ps (half2).
__global__ __launch_bounds__(256) void l1_reduce_mlp(
    const float4* __restrict__ partial, const uint2* __restrict__ xs,
    const float* __restrict__ dinv,
    const float* __restrict__ W1, const float* __restrict__ b1,
    const float* __restrict__ W2, unsigned int* __restrict__ ps, int N) {
    __shared__ float sW1[256];
    __shared__ float sb1[64];
    __shared__ float sW2[128];
    int t = threadIdx.x;
    sW1[t] = W1[t];
    if (t < 64) sb1[t] = b1[t];
    if (t < 128) sW2[t] = W2[t];
    __syncthreads();
    int i = blockIdx.x * 256 + t;
    if (i >= N) return;
    int bucket = i >> BB, j = i & BMASK;
    float axs = 0.0f, ays = 0.0f, azs = 0.0f, aws = 0.0f;
    size_t kb = (size_t)bucket * SLICES;
    for (int s = 0; s < SLICES; ++s) {
        float4 v = partial[(kb + s) * BSZ + j];
        axs += v.x; ays += v.y; azs += v.z; aws += v.w;
    }
    float di = dinv[i];
    uint2 raw = xs[i];  // self-loop (quantized, consistent)
    __half2 h01 = u2h(raw.x), h23 = u2h(raw.y);
    float ax = (axs + __half2float(__low2half(h01))) * di;
    float ay = (ays + __half2float(__high2half(h01))) * di;
    float az = (azs + __half2float(__low2half(h23))) * di;
    float aw = (aws + __half2float(__high2half(h23))) * di;
    float p0 = 0.0f, p1 = 0.0f;
#pragma unroll
    for (int k = 0; k < 64; ++k) {
        float h = fmaf(ax, sW1[k],
                  fmaf(ay, sW1[64 + k],
                  fmaf(az, sW1[128 + k],
                  fmaf(aw, sW1[192 + k], sb1[k]))));
        h = fmaxf(h, 0.0f);
        p0 = fmaf(h, sW2[2 * k + 0], p0);
        p1 = fmaf(h, sW2[2 * k + 1], p1);
    }
    ps[i] = h2u(__halves2half2(__float2half_rn(p0 * di), __float2half_rn(p1 * di)));
}

// Layer-2 gather: same XCD-pinned mapping; ps slice (1 MB) is L2-resident.
__global__ __launch_bounds__(256) void l2_gather(
    const unsigned int* __restrict__ ebin2, const unsigned short* __restrict__ rp16,
    const unsigned int* __restrict__ bktbase, const unsigned int* __restrict__ ps,
    float2* __restrict__ partial) {
    int bid = blockIdx.x, t = threadIdx.x;
    int r = bid & 7, s = r & 3, half = r >> 2, q = bid >> 3;
    int b = q >> 2, sub = (half << 2) | (q & 3);
    int idx = (((b << 2) + s) << BB) + (sub << 8) + t;
    unsigned int kb = bktbase[b];
    unsigned int st = kb + rp16[idx];
    bool last = (s == SLICES - 1) && (sub == 7) && (t == 255);
    unsigned int en = last ? bktbase[b + 1] : kb + rp16[idx + 1];
    float s0 = 0.0f, s1 = 0.0f;
    unsigned int e = st;
    for (; e + 2 <= en; e += 2) {
        unsigned int a = ebin2[e], bb = ebin2[e + 1];
        unsigned int ra = ps[a], rb2 = ps[bb];
        __half2 ha = u2h(ra), hb = u2h(rb2);
        s0 += __half2float(__low2half(ha)) + __half2float(__low2half(hb));
        s1 += __half2float(__high2half(ha)) + __half2float(__high2half(hb));
    }
    if (e < en) {
        __half2 h = u2h(ps[ebin2[e]]);
        s0 += __half2float(__low2half(h));
        s1 += __half2float(__high2half(h));
    }
    partial[idx] = make_float2(s0, s1);
}

// Layer-2 reduce + self-loop + bias -> out.
__global__ __launch_bounds__(256) void l2_reduce(
    const float2* __restrict__ partial, const unsigned int* __restrict__ ps,
    const float* __restrict__ dinv, const float* __restrict__ b2,
    float2* __restrict__ out, int N) {
    int i = blockIdx.x * 256 + threadIdx.x;
    if (i >= N) return;
    int bucket = i >> BB, j = i & BMASK;
    float s0 = 0.0f, s1 = 0.0f;
    size_t kb = (size_t)bucket * SLICES;
    for (int s = 0; s < SLICES; ++s) {
        float2 v = partial[(kb + s) * BSZ + j];
        s0 += v.x; s1 += v.y;
    }
    float di = dinv[i];
    __half2 h = u2h(ps[i]);  // self-loop
    float2 rr;
    rr.x = fmaf(s0 + __half2float(__low2half(h)), di, b2[0]);
    rr.y = fmaf(s1 + __half2float(__high2half(h)), di, b2[1]);
    out[i] = rr;
}

static inline size_t align256(size_t v) { return (v + 255) & ~(size_t)255; }

extern "C" void kernel_launch(void* const* d_in, const int* in_sizes, int n_in,
                              void* d_out, int out_size, void* d_ws, size_t ws_size,
                              hipStream_t stream) {
    const float* x  = (const float*)d_in[0];
    const int*   ei = (const int*)d_in[1];
    const float* W1 = (const float*)d_in[2];
    const float* b1 = (const float*)d_in[3];
    const float* W2 = (const float*)d_in[4];
    const float* b2 = (const float*)d_in[5];

    const int N = in_sizes[0] / 4;
    const int E = in_sizes[1] / 2;
    const int NB = (N + BSZ - 1) >> BB;
    const int NB1 = NB + 1;
    const int NBLKr = (E + CHUNK - 1) / CHUNK;

    // Persistent buffers, then region R where partial ALIASES {stage, lofs}
    // (stage/lofs are dead before l1_gather writes partial).
    size_t o = 0;
    size_t o_bkt  = o; o = align256(o + (size_t)NB1 * 4);                  // bktbase
    size_t o_dinv = o; o = align256(o + (size_t)N * 4);                    // dinv
    size_t o_xs   = o; o = align256(o + (size_t)N * 8);                    // xs
    size_t o_ps   = o; o = align256(o + (size_t)N * 4);                    // ps
    size_t o_eb2  = o; o = align256(o + (size_t)E * 4);                    // ebin2
    size_t o_rp   = o; o = align256(o + (size_t)NB * SKEYS * 2);           // rp16
    size_t o_R    = o;                                                     // region R
    size_t o_stage = o_R;
    size_t o_lofs  = align256(o_stage + (size_t)NBLKr * CHUNK * 4);

    char* ws = (char*)d_ws;
    unsigned int*   bktbase = (unsigned int*)(ws + o_bkt);
    float*          dinv    = (float*)(ws + o_dinv);
    uint2*          xs      = (uint2*)(ws + o_xs);
    unsigned int*   ps      = (unsigned int*)(ws + o_ps);
    unsigned int*   ebin2   = (unsigned int*)(ws + o_eb2);
    unsigned short* rp16    = (unsigned short*)(ws + o_rp);
    unsigned int*   stage   = (unsigned int*)(ws + o_stage);
    unsigned int*   lofs    = (unsigned int*)(ws + o_lofs);
    float4*         part4   = (float4*)(ws + o_R);   // aliases stage/lofs
    float2*         part2   = (float2*)(ws + o_R);   // sequential phases

    local_sort<<<NBLKr, BTHREADS, 0, stream>>>(ei, E, NB, lofs, stage);
    rowsum<<<NB1, BTHREADS, 0, stream>>>(lofs, bktbase, NBLKr, NB1);
    sort2_deg<<<NB, GTHREADS, 0, stream>>>(stage, lofs, bktbase, (const float4*)x,
                                           dinv, xs, ebin2, rp16, N, NBLKr, NB);
    l1_gather<<<NB * 32, 256, 0, stream>>>(ebin2, rp16, bktbase, xs, part4);
    l1_reduce_mlp<<<(N + 255) / 256, 256, 0, stream>>>(part4, xs, dinv, W1, b1, W2, ps, N);
    l2_gather<<<NB * 32, 256, 0, stream>>>(ebin2, rp16, bktbase, ps, part2);
    l2_reduce<<<(N + 255) / 256, 256, 0, stream>>>(part2, ps, dinv, b2, (float2*)d_out, N);
}

// Round 7
// 358.728 us; speedup vs baseline: 1.8786x; 1.3738x over previous
//
#include <hip/hip_runtime.h>
#include <hip/hip_fp16.h>

#define NBLK 1024        // blocks for edge-streaming passes
#define BTHREADS 256
#define CHUNK 7936       // edges per chunk_sort_flush block (31 KB LDS staging)
#define BB 11            // bucket bits: 2048 nodes per bucket
#define BSZ (1 << BB)
#define BMASK (BSZ - 1)
#define MAXNB 512        // max dst-buckets (N <= 1,048,576)
#define SLICES 4         // src slices (xs slice = 2 MB -> per-XCD L2-resident)
#define SSHIFT 18        // src slice = src >> 18 (N <= 2^20)
#define SKEYS (SLICES * BSZ)   // 8192 13-bit sort keys per bucket
#define S2T 1024         // sort2_deg threads
#define STGCAP 17408     // LDS staging cap for one bucket (+8 sigma of E/NB)
#define CP(i) ((i) + ((i) >> 5))   // +1-per-32 pad: breaks LDS bank conflicts

// ---------------- helpers ----------------
__device__ __forceinline__ int detect64(const int* __restrict__ ei) {
    return (ei[1] | ei[3] | ei[5] | ei[7] | ei[9] | ei[11] | ei[13] | ei[15]) == 0;
}
__device__ __forceinline__ int load_src(const int* __restrict__ ei, int e, int is64) {
    return is64 ? ei[2 * (size_t)e] : ei[(size_t)e];
}
__device__ __forceinline__ int load_dst(const int* __restrict__ ei, int E, int e, int is64) {
    return is64 ? ei[2 * ((size_t)E + e)] : ei[(size_t)E + e];
}
__device__ __forceinline__ unsigned int h2u(__half2 h) {
    union { __half2 h; unsigned int u; } c; c.h = h; return c.u;
}
__device__ __forceinline__ __half2 u2h(unsigned int u) {
    union { __half2 h; unsigned int u; } c; c.u = u; return c.h;
}

// Zero the global histogram (graph-capture-safe replacement for memset).
__global__ __launch_bounds__(512) void zero_hist(unsigned int* __restrict__ ghist, int NB) {
    int t = threadIdx.x;
    if (t < NB) ghist[t] = 0;
}

// Global dst-bucket histogram: per-block LDS hist, one atomicAdd per bucket.
__global__ __launch_bounds__(BTHREADS) void hist_global(
    const int* __restrict__ ei, int E, int NB, unsigned int* __restrict__ ghist) {
    __shared__ unsigned int cnt[MAXNB];
    int t = threadIdx.x, blk = blockIdx.x;
    for (int u = t; u < NB; u += BTHREADS) cnt[u] = 0;
    __syncthreads();
    int is64 = detect64(ei);
    int chunk = (E + NBLK - 1) / NBLK;
    int lo = blk * chunk;
    int hi = lo + chunk; if (hi > E) hi = E;
    for (int e = lo + t; e < hi; e += BTHREADS) {
        int d = load_dst(ei, E, e, is64);
        atomicAdd(&cnt[d >> BB], 1u);
    }
    __syncthreads();
    for (int u = t; u < NB; u += BTHREADS)
        if (cnt[u]) atomicAdd(&ghist[u], cnt[u]);
}

// Exclusive scan of ghist -> bktbase (+sentinel) and gcur (mutable cursors).
__global__ __launch_bounds__(512) void scan_init(
    const unsigned int* __restrict__ ghist, unsigned int* __restrict__ bktbase,
    unsigned int* __restrict__ gcur, int NB) {
    __shared__ unsigned int s[512];
    int t = threadIdx.x;
    unsigned int v = (t < NB) ? ghist[t] : 0;
    s[t] = v;
    __syncthreads();
    for (int o = 1; o < 512; o <<= 1) {
        unsigned int x = (t >= o) ? s[t - o] : 0;
        __syncthreads();
        s[t] += x;
        __syncthreads();
    }
    unsigned int excl = t ? s[t - 1] : 0;
    if (t < NB) { bktbase[t] = excl; gcur[t] = excl; }
    if (t == NB - 1) bktbase[NB] = excl + v;  // sentinel = E
}

// chunk_sort_flush: LDS bucket-sort one 7936-edge chunk, atomically reserve
// per-bucket space in the COMPACT global ebin (one atomicAdd per (chunk,bucket)
// -> only ~NB open tail-lines chip-wide, L2-resident), then flush each run as
// a contiguous burst. No scattered-dword global stores anywhere.
__global__ __launch_bounds__(BTHREADS) void chunk_sort_flush(
    const int* __restrict__ ei, int E, int NB,
    unsigned int* __restrict__ gcur, unsigned int* __restrict__ ebin) {
    __shared__ unsigned int cnt[MAXNB];     // counts -> lstart -> (post-scatter) lstart[u+1]
    __shared__ unsigned int ssum[BTHREADS];
    __shared__ unsigned int stg[CHUNK];     // 31 KB
    __shared__ unsigned int gdst[MAXNB];    // reserved_base - lstart (uint wrap ok)
    int t = threadIdx.x, blk = blockIdx.x;
    for (int u = t; u < NB; u += BTHREADS) cnt[u] = 0;
    __syncthreads();
    int is64 = detect64(ei);
    int lo = blk * CHUNK;
    int hi = lo + CHUNK; if (hi > E) hi = E;
    for (int e = lo + t; e < hi; e += BTHREADS) {
        int d = load_dst(ei, E, e, is64);
        atomicAdd(&cnt[d >> BB], 1u);
    }
    __syncthreads();
    // exclusive scan over NB counters (2 per thread, NB <= 512)
    unsigned int v0 = (2 * t < NB) ? cnt[2 * t] : 0;
    unsigned int v1 = (2 * t + 1 < NB) ? cnt[2 * t + 1] : 0;
    ssum[t] = v0 + v1;
    __syncthreads();
    for (int o = 1; o < BTHREADS; o <<= 1) {
        unsigned int x2 = (t >= o) ? ssum[t - o] : 0;
        __syncthreads();
        ssum[t] += x2;
        __syncthreads();
    }
    unsigned int base = t ? ssum[t - 1] : 0;
    if (2 * t < NB)     cnt[2 * t]     = base;
    if (2 * t + 1 < NB) cnt[2 * t + 1] = base + v0;
    __syncthreads();
    // scatter into LDS staging (LDS absorbs the scatter at bank granularity)
    for (int e = lo + t; e < hi; e += BTHREADS) {
        int s = load_src(ei, e, is64);
        int d = load_dst(ei, E, e, is64);
        unsigned int pos = atomicAdd(&cnt[d >> BB], 1u);
        stg[pos] = ((unsigned int)s << BB) | (unsigned int)(d & BMASK);
    }
    __syncthreads();
    // reserve: all buckets in parallel (atomics all in flight at once).
    // post-scatter invariant: cnt[u] == lstart[u+1]; lstart[u] == (u?cnt[u-1]:0)
    for (int u = t; u < NB; u += BTHREADS) {
        unsigned int lst = u ? cnt[u - 1] : 0;
        unsigned int L = cnt[u] - lst;
        if (L) gdst[u] = atomicAdd(&gcur[u], L) - lst;
    }
    __syncthreads();
    // wave-cooperative flush: contiguous run per bucket
    int w = t >> 6, lane = t & 63, nw = BTHREADS >> 6;
    for (int u = w; u < NB; u += nw) {
        unsigned int lst = u ? cnt[u - 1] : 0;
        unsigned int en = cnt[u];
        for (unsigned int j = lst + lane; j < en; j += 64)
            ebin[gdst[u] + j] = stg[j];
    }
}

// Per bucket: CONTIGUOUS two-pass read of ebin[bktbase[b],bktbase[b+1]),
// 13-bit counting sort by (srcslice<<11 | dstlow) staged in LDS, coalesced
// flush to ebin2 (src ids), u16 row offsets rp16, AND degree->dinv->xs prep.
__global__ __launch_bounds__(S2T) void sort2_deg(
    const unsigned int* __restrict__ ebin, const unsigned int* __restrict__ bktbase,
    const float4* __restrict__ x, float* __restrict__ dinv, uint2* __restrict__ xs,
    unsigned int* __restrict__ ebin2, unsigned short* __restrict__ rp16, int N) {
    __shared__ unsigned int cnt[CP(SKEYS)];   // 33 KB, bank-padded
    __shared__ unsigned int ssum[S2T];        // 4 KB
    __shared__ unsigned int stg2[STGCAP];     // 68 KB
    int b = blockIdx.x, t = threadIdx.x;
    for (int j = t; j < CP(SKEYS); j += S2T) cnt[j] = 0;
    __syncthreads();
    unsigned int base = bktbase[b];
    int ne = (int)(bktbase[b + 1] - base);
    // count phase: contiguous coalesced read
    for (int i = t; i < ne; i += S2T) {
        unsigned int rec = ebin[base + i];
        unsigned int k13 = ((rec >> (BB + SSHIFT)) << BB) | (rec & BMASK);
        atomicAdd(&cnt[CP(k13)], 1u);
    }
    __syncthreads();
    // degree (sum over 4 slices) -> dinv + quantized scaled features
    int g0 = b << BB;
    int nn = N - g0; if (nn > BSZ) nn = BSZ;
    for (int j = t; j < nn; j += S2T) {
        unsigned int deg = cnt[CP(j)] + cnt[CP(BSZ + j)] + cnt[CP(2 * BSZ + j)] + cnt[CP(3 * BSZ + j)];
        int g = g0 + j;
        float di = rsqrtf((float)(deg + 1u));
        dinv[g] = di;
        float4 v = x[g];
        uint2 p;
        p.x = h2u(__halves2half2(__float2half_rn(v.x * di), __float2half_rn(v.y * di)));
        p.y = h2u(__halves2half2(__float2half_rn(v.z * di), __float2half_rn(v.w * di)));
        xs[g] = p;
    }
    // exclusive scan of 8192 counters: 8 contiguous per thread + block scan
    unsigned int loc[8];
    unsigned int s = 0;
#pragma unroll
    for (int j = 0; j < 8; ++j) { loc[j] = s; s += cnt[CP(8 * t + j)]; }
    ssum[t] = s;
    __syncthreads();
    for (int o = 1; o < S2T; o <<= 1) {
        unsigned int v = (t >= o) ? ssum[t - o] : 0;
        __syncthreads();
        ssum[t] += v;
        __syncthreads();
    }
    unsigned int tb = t ? ssum[t - 1] : 0;
    size_t rb = (size_t)b * SKEYS;
#pragma unroll
    for (int j = 0; j < 8; ++j)
        rp16[rb + 8 * t + j] = (unsigned short)(tb + loc[j]);
#pragma unroll
    for (int j = 0; j < 8; ++j) cnt[CP(8 * t + j)] = tb + loc[j];
    __syncthreads();
    // scatter phase: re-read (L2/L3-hot), scatter src ids into LDS staging
    for (int i = t; i < ne; i += S2T) {
        unsigned int rec = ebin[base + i];
        unsigned int k13 = ((rec >> (BB + SSHIFT)) << BB) | (rec & BMASK);
        unsigned int pos = atomicAdd(&cnt[CP(k13)], 1u);
        unsigned int v = rec >> BB;   // src node id
        if (pos < STGCAP) stg2[pos] = v;
        else ebin2[base + pos] = v;   // overflow fallback (memory-safe, ~never)
    }
    __syncthreads();
    // coalesced flush to ebin2
    int m = ne < STGCAP ? ne : STGCAP;
    for (int j = t; j < m; j += S2T) ebin2[base + j] = stg2[j];
}

// Block remap: bid%8 determines XCD (round-robin dispatch); pin slice = (bid&3)
// so each XCD's gather working set is ONE 2 MB slice (round-2-proven mapping).
__global__ __launch_bounds__(256) void l1_gather(
    const unsigned int* __restrict__ ebin2, const unsigned short* __restrict__ rp16,
    const unsigned int* __restrict__ bktbase, const uint2* __restrict__ xs,
    float4* __restrict__ partial) {
    int bid = blockIdx.x, t = threadIdx.x;
    int r = bid & 7, s = r & 3, half = r >> 2, q = bid >> 3;
    int b = q >> 2, sub = (half << 2) | (q & 3);
    int idx = (((b << 2) + s) << BB) + (sub << 8) + t;
    unsigned int kb = bktbase[b];
    unsigned int st = kb + rp16[idx];
    bool last = (s == SLICES - 1) && (sub == 7) && (t == 255);
    unsigned int en = last ? bktbase[b + 1] : kb + rp16[idx + 1];
    float ax = 0.0f, ay = 0.0f, az = 0.0f, aw = 0.0f;
    unsigned int e = st;
    for (; e + 2 <= en; e += 2) {
        unsigned int s0 = ebin2[e], s1 = ebin2[e + 1];
        uint2 r0 = xs[s0], r1 = xs[s1];
        __half2 a01 = u2h(r0.x), a23 = u2h(r0.y);
        __half2 b01 = u2h(r1.x), b23 = u2h(r1.y);
        ax += __half2float(__low2half(a01)) + __half2float(__low2half(b01));
        ay += __half2float(__high2half(a01)) + __half2float(__high2half(b01));
        az += __half2float(__low2half(a23)) + __half2float(__low2half(b23));
        aw += __half2float(__high2half(a23)) + __half2float(__high2half(b23));
    }
    if (e < en) {
        uint2 rr = xs[ebin2[e]];
        __half2 a01 = u2h(rr.x), a23 = u2h(rr.y);
        ax += __half2float(__low2half(a01));
        ay += __half2float(__high2half(a01));
        az += __half2float(__low2half(a23));
        aw += __half2float(__high2half(a23));
    }
    partial[idx] = make_float4(ax, ay, az, aw);
}

// Layer-1 reduce (sum 4 slice partials) + self-loop + fused MLP -> ps (half2).
__global__ __launch_bounds__(256) void l1_reduce_mlp(
    const float4* __restrict__ partial, const uint2* __restrict__ xs,
    const float* __restrict__ dinv,
    const float* __restrict__ W1, const float* __restrict__ b1,
    const float* __restrict__ W2, unsigned int* __restrict__ ps, int N) {
    __shared__ float sW1[256];
    __shared__ float sb1[64];
    __shared__ float sW2[128];
    int t = threadIdx.x;
    sW1[t] = W1[t];
    if (t < 64) sb1[t] = b1[t];
    if (t < 128) sW2[t] = W2[t];
    __syncthreads();
    int i = blockIdx.x * 256 + t;
    if (i >= N) return;
    int bucket = i >> BB, j = i & BMASK;
    float axs = 0.0f, ays = 0.0f, azs = 0.0f, aws = 0.0f;
    size_t kb = (size_t)bucket * SLICES;
    for (int s = 0; s < SLICES; ++s) {
        float4 v = partial[(kb + s) * BSZ + j];
        axs += v.x; ays += v.y; azs += v.z; aws += v.w;
    }
    float di = dinv[i];
    uint2 raw = xs[i];  // self-loop (quantized, consistent)
    __half2 h01 = u2h(raw.x), h23 = u2h(raw.y);
    float ax = (axs + __half2float(__low2half(h01))) * di;
    float ay = (ays + __half2float(__high2half(h01))) * di;
    float az = (azs + __half2float(__low2half(h23))) * di;
    float aw = (aws + __half2float(__high2half(h23))) * di;
    float p0 = 0.0f, p1 = 0.0f;
#pragma unroll
    for (int k = 0; k < 64; ++k) {
        float h = fmaf(ax, sW1[k],
                  fmaf(ay, sW1[64 + k],
                  fmaf(az, sW1[128 + k],
                  fmaf(aw, sW1[192 + k], sb1[k]))));
        h = fmaxf(h, 0.0f);
        p0 = fmaf(h, sW2[2 * k + 0], p0);
        p1 = fmaf(h, sW2[2 * k + 1], p1);
    }
    ps[i] = h2u(__halves2half2(__float2half_rn(p0 * di), __float2half_rn(p1 * di)));
}

// Layer-2 gather: same XCD-pinned mapping; ps slice (1 MB) is L2-resident.
__global__ __launch_bounds__(256) void l2_gather(
    const unsigned int* __restrict__ ebin2, const unsigned short* __restrict__ rp16,
    const unsigned int* __restrict__ bktbase, const unsigned int* __restrict__ ps,
    float2* __restrict__ partial) {
    int bid = blockIdx.x, t = threadIdx.x;
    int r = bid & 7, s = r & 3, half = r >> 2, q = bid >> 3;
    int b = q >> 2, sub = (half << 2) | (q & 3);
    int idx = (((b << 2) + s) << BB) + (sub << 8) + t;
    unsigned int kb = bktbase[b];
    unsigned int st = kb + rp16[idx];
    bool last = (s == SLICES - 1) && (sub == 7) && (t == 255);
    unsigned int en = last ? bktbase[b + 1] : kb + rp16[idx + 1];
    float s0 = 0.0f, s1 = 0.0f;
    unsigned int e = st;
    for (; e + 2 <= en; e += 2) {
        unsigned int a = ebin2[e], bb = ebin2[e + 1];
        unsigned int ra = ps[a], rb2 = ps[bb];
        __half2 ha = u2h(ra), hb = u2h(rb2);
        s0 += __half2float(__low2half(ha)) + __half2float(__low2half(hb));
        s1 += __half2float(__high2half(ha)) + __half2float(__high2half(hb));
    }
    if (e < en) {
        __half2 h = u2h(ps[ebin2[e]]);
        s0 += __half2float(__low2half(h));
        s1 += __half2float(__high2half(h));
    }
    partial[idx] = make_float2(s0, s1);
}

// Layer-2 reduce + self-loop + bias -> out.
__global__ __launch_bounds__(256) void l2_reduce(
    const float2* __restrict__ partial, const unsigned int* __restrict__ ps,
    const float* __restrict__ dinv, const float* __restrict__ b2,
    float2* __restrict__ out, int N) {
    int i = blockIdx.x * 256 + threadIdx.x;
    if (i >= N) return;
    int bucket = i >> BB, j = i & BMASK;
    float s0 = 0.0f, s1 = 0.0f;
    size_t kb = (size_t)bucket * SLICES;
    for (int s = 0; s < SLICES; ++s) {
        float2 v = partial[(kb + s) * BSZ + j];
        s0 += v.x; s1 += v.y;
    }
    float di = dinv[i];
    __half2 h = u2h(ps[i]);  // self-loop
    float2 rr;
    rr.x = fmaf(s0 + __half2float(__low2half(h)), di, b2[0]);
    rr.y = fmaf(s1 + __half2float(__high2half(h)), di, b2[1]);
    out[i] = rr;
}

static inline size_t align256(size_t v) { return (v + 255) & ~(size_t)255; }

extern "C" void kernel_launch(void* const* d_in, const int* in_sizes, int n_in,
                              void* d_out, int out_size, void* d_ws, size_t ws_size,
                              hipStream_t stream) {
    const float* x  = (const float*)d_in[0];
    const int*   ei = (const int*)d_in[1];
    const float* W1 = (const float*)d_in[2];
    const float* b1 = (const float*)d_in[3];
    const float* W2 = (const float*)d_in[4];
    const float* b2 = (const float*)d_in[5];

    const int N = in_sizes[0] / 4;
    const int E = in_sizes[1] / 2;
    const int NB = (N + BSZ - 1) >> BB;
    const int NB1 = NB + 1;
    const int NBLKc = (E + CHUNK - 1) / CHUNK;

    // Persistent buffers, then region R where partial ALIASES ebin
    // (ebin is dead after sort2_deg; partial written by l1_gather after).
    size_t o = 0;
    size_t o_bkt  = o; o = align256(o + (size_t)NB1 * 4);                  // bktbase
    size_t o_cur  = o; o = align256(o + (size_t)NB * 4);                   // gcur
    size_t o_gh   = o; o = align256(o + (size_t)NB * 4);                   // ghist
    size_t o_dinv = o; o = align256(o + (size_t)N * 4);                    // dinv
    size_t o_xs   = o; o = align256(o + (size_t)N * 8);                    // xs
    size_t o_ps   = o; o = align256(o + (size_t)N * 4);                    // ps
    size_t o_eb2  = o; o = align256(o + (size_t)E * 4);                    // ebin2
    size_t o_rp   = o; o = align256(o + (size_t)NB * SKEYS * 2);           // rp16
    size_t o_R    = o;                                                     // region R
    size_t o_ebin = o_R;                                                   // ebin (32 MB)

    char* ws = (char*)d_ws;
    unsigned int*   bktbase = (unsigned int*)(ws + o_bkt);
    unsigned int*   gcur    = (unsigned int*)(ws + o_cur);
    unsigned int*   ghist   = (unsigned int*)(ws + o_gh);
    float*          dinv    = (float*)(ws + o_dinv);
    uint2*          xs      = (uint2*)(ws + o_xs);
    unsigned int*   ps      = (unsigned int*)(ws + o_ps);
    unsigned int*   ebin2   = (unsigned int*)(ws + o_eb2);
    unsigned short* rp16    = (unsigned short*)(ws + o_rp);
    unsigned int*   ebin    = (unsigned int*)(ws + o_ebin);
    float4*         part4   = (float4*)(ws + o_R);   // aliases ebin
    float2*         part2   = (float2*)(ws + o_R);   // sequential phases

    zero_hist<<<1, 512, 0, stream>>>(ghist, NB);
    hist_global<<<NBLK, BTHREADS, 0, stream>>>(ei, E, NB, ghist);
    scan_init<<<1, 512, 0, stream>>>(ghist, bktbase, gcur, NB);
    chunk_sort_flush<<<NBLKc, BTHREADS, 0, stream>>>(ei, E, NB, gcur, ebin);
    sort2_deg<<<NB, S2T, 0, stream>>>(ebin, bktbase, (const float4*)x,
                                      dinv, xs, ebin2, rp16, N);
    l1_gather<<<NB * 32, 256, 0, stream>>>(ebin2, rp16, bktbase, xs, part4);
    l1_reduce_mlp<<<(N + 255) / 256, 256, 0, stream>>>(part4, xs, dinv, W1, b1, W2, ps, N);
    l2_gather<<<NB * 32, 256, 0, stream>>>(ebin2, rp16, bktbase, ps, part2);
    l2_reduce<<<(N + 255) / 256, 256, 0, stream>>>(part2, ps, dinv, b2, (float2*)d_out, N);
}